// Round 9
// baseline (1889.135 us; speedup 1.0000x reference)
//
#include <hip/hip_runtime.h>
#include <cstdint>
#include <cstddef>

// DeltaNetMolecular R9: edge kernel with DEPTH-2 gather pipeline ordered so no
// weight vmcnt-wait drains the in-flight gathers (2 chunks of latency cover,
// ~2x memory-level parallelism). gemm_proj computes A+B chunk per block (halved
// fH re-reads). Everything else from R8.

#define DEV __device__ __forceinline__

typedef __attribute__((ext_vector_type(8))) short bf16x8;
typedef __attribute__((ext_vector_type(4))) float f32x4;

DEV float siluf(float x) { return x / (1.f + __expf(-x)); }

DEV unsigned short f2bf(float f) {
  unsigned u = __float_as_uint(f);
  unsigned r = u + 0x7FFFu + ((u >> 16) & 1u);
  return (unsigned short)(r >> 16);
}
DEV float bf2f(unsigned short h) { return __uint_as_float(((unsigned)h) << 16); }

DEV f32x4 mfma16(bf16x8 a, bf16x8 b, f32x4 c) {
  return __builtin_amdgcn_mfma_f32_16x16x32_bf16(a, b, c, 0, 0, 0);
}

DEV void unpack8(bf16x8 v, float* o) {
#pragma unroll
  for (int j = 0; j < 8; ++j) o[j] = bf2f((unsigned short)v[j]);
}

// ------------------------------------------------- gather emb (+bf16 copy)
__global__ __launch_bounds__(256) void k_gather(const int* __restrict__ atomids,
                                                const float* __restrict__ emb,
                                                float* __restrict__ feats_all,
                                                unsigned short* __restrict__ fH, int N) {
  int idx = blockIdx.x * 256 + threadIdx.x;
  if (idx >= N * 128) return;
  int i = idx >> 7, j = idx & 127;
  float v = emb[atomids[i] * 128 + j];
  size_t o = (size_t)i * 768 + j;
  feats_all[o] = v;
  fH[o] = f2bf(v);
}

// --------------------------------------------------- edge dist + dst histogram
__global__ __launch_bounds__(256) void k_edge_prep(const float* __restrict__ coords,
                                                   const int* __restrict__ ei, int E,
                                                   float* __restrict__ d_arr,
                                                   int* __restrict__ cnt) {
  int e = blockIdx.x * 256 + threadIdx.x;
  if (e >= E) return;
  int s = ei[e], t = ei[E + e];
  float dx = coords[3 * s + 0] - coords[3 * t + 0];
  float dy = coords[3 * s + 1] - coords[3 * t + 1];
  float dz = coords[3 * s + 2] - coords[3 * t + 2];
  d_arr[e] = dx * dx + dy * dy + dz * dz;
  atomicAdd(&cnt[t], 1);
}

// -------------------- single-block scan, shuffle-based (2 barriers total)
__global__ __launch_bounds__(1024) void k_scan2(const int* __restrict__ cnt, int N,
                                                int* __restrict__ cursor,
                                                float* __restrict__ degf) {
  __shared__ int wsum[16];
  int tid = threadIdx.x;
  int chunk = (N + 1023) >> 10;
  int lo = tid * chunk, hi = min(N, lo + chunk);
  int s = 0;
  for (int i = lo; i < hi; ++i) s += cnt[i];
  int lane = tid & 63, wv = tid >> 6;
  int v = s;
#pragma unroll
  for (int off = 1; off < 64; off <<= 1) {
    int u = __shfl_up(v, off, 64);
    if (lane >= off) v += u;
  }
  if (lane == 63) wsum[wv] = v;
  __syncthreads();
  if (wv == 0 && lane < 16) {
    int w = wsum[lane];
#pragma unroll
    for (int off = 1; off < 16; off <<= 1) {
      int u = __shfl_up(w, off, 16);
      if (lane >= off) w += u;
    }
    wsum[lane] = w;
  }
  __syncthreads();
  int run = (wv ? wsum[wv - 1] : 0) + v - s;  // exclusive prefix
  for (int i = lo; i < hi; ++i) {
    int c = cnt[i];
    cursor[i] = run;
    degf[i] = fmaxf((float)c, 1.f);
    run += c;
  }
}

// ------------------------------------------------------- scatter sorted edges
__global__ __launch_bounds__(256) void k_scatter(const int* __restrict__ ei, int E,
                                                 const float* __restrict__ d_arr,
                                                 int* __restrict__ cursor,
                                                 int* __restrict__ ssrc,
                                                 int* __restrict__ sdst,
                                                 float* __restrict__ sd) {
  int e = blockIdx.x * 256 + threadIdx.x;
  if (e >= E) return;
  int s = ei[e], t = ei[E + e];
  int p = atomicAdd(&cursor[t], 1);
  ssrc[p] = s;
  sdst[p] = t;
  sd[p] = d_arr[e];
}

// ------------------------------------ merged weight prepack (one launch)
struct PPJob {
  const float* W;
  unsigned short* hi;
  unsigned short* lo;
  unsigned long long wStride, oStride;
  int ldw, K, Kpad, Nc, Npad, layers;
};
struct PPJobs { PPJob j[11]; };

__global__ __launch_bounds__(256) void k_prepack_all(PPJobs jobs) {
  PPJob jb = jobs.j[blockIdx.y];
  long long per = (long long)jb.Npad * jb.Kpad;
  long long idx = (long long)blockIdx.x * 256 + threadIdx.x;
  if (idx >= per * jb.layers) return;
  int layer = (int)(idx / per);
  int r = (int)(idx - (long long)layer * per);
  const float* W = jb.W + (size_t)layer * jb.wStride;
  int n = r / jb.Kpad, k = r - n * jb.Kpad;
  float v = (n < jb.Nc && k < jb.K) ? W[(size_t)k * jb.ldw + n] : 0.f;
  unsigned short h = f2bf(v);
  jb.hi[(size_t)layer * jb.oStride + r] = h;
  jb.lo[(size_t)layer * jb.oStride + r] = f2bf(v - bf2f(h));
}

// --------- bf16 MFMA GEMM: A bf16, B hi/lo x2, M=64 per block (grid-rich)
__global__ __launch_bounds__(256) void gemm_bf(
    const unsigned short* __restrict__ AH, int lda,
    const unsigned short* __restrict__ BH, const unsigned short* __restrict__ BL, int ldb,
    const float* __restrict__ bias,
    float* __restrict__ C, int ldc,
    unsigned short* __restrict__ CH, int ldch,
    int M, int Ncols, int K, int actOut, int actA) {
  const int t = threadIdx.x;
  const int wave = t >> 6, lane = t & 63;
  const int nl = lane & 15, quad = lane >> 4;
  const int bm = blockIdx.x * 64 + wave * 16;
  const int bn = blockIdx.y * 64;
  f32x4 zero = {0.f, 0.f, 0.f, 0.f};
  f32x4 acc[4] = {zero, zero, zero, zero};
  for (int kb = 0; kb < K; kb += 32) {
    bf16x8 ah;
    int row = bm + nl;
    if (row < M) {
      ah = *(const bf16x8*)(AH + (size_t)row * lda + kb + quad * 8);
      if (actA) {
#pragma unroll
        for (int j = 0; j < 8; ++j)
          ah[j] = (short)f2bf(siluf(bf2f((unsigned short)ah[j])));
      }
    } else {
#pragma unroll
      for (int j = 0; j < 8; ++j) ah[j] = 0;
    }
#pragma unroll
    for (int tn = 0; tn < 4; ++tn) {
      size_t boff = (size_t)(bn + tn * 16 + nl) * ldb + kb + quad * 8;
      bf16x8 bh = *(const bf16x8*)(BH + boff);
      bf16x8 bl = *(const bf16x8*)(BL + boff);
      acc[tn] = mfma16(ah, bh, acc[tn]);
      acc[tn] = mfma16(ah, bl, acc[tn]);
    }
  }
#pragma unroll
  for (int tn = 0; tn < 4; ++tn) {
    int c = bn + tn * 16 + nl;
    float bv = (bias && c < Ncols) ? bias[c] : 0.f;
#pragma unroll
    for (int r = 0; r < 4; ++r) {
      int rr = bm + quad * 4 + r;
      if (rr >= M) continue;
      float v = acc[tn][r] + bv;
      if (actOut) v = siluf(v);
      if (C && c < Ncols) C[(size_t)rr * ldc + c] = v;
      if (CH && c < Ncols) CH[(size_t)rr * ldch + c] = f2bf(v);
    }
  }
}

// --------- A+B projection: block = 64 rows x chunk yp; tn<4 -> C1, tn>=4 -> C2
__global__ __launch_bounds__(256) void gemm_proj(
    const unsigned short* __restrict__ AH, int lda,
    const unsigned short* __restrict__ B1H, const unsigned short* __restrict__ B1L,
    const unsigned short* __restrict__ B2H, const unsigned short* __restrict__ B2L,
    const float* __restrict__ bias1,
    unsigned short* __restrict__ C1, unsigned short* __restrict__ C2,
    int planeN, int M) {
  const int yp = blockIdx.y;  // chunk 0..10
  const int t = threadIdx.x;
  const int wave = t >> 6, lane = t & 63;
  const int nl = lane & 15, quad = lane >> 4;
  const int bm = blockIdx.x * 64 + wave * 16;
  f32x4 zero = {0.f, 0.f, 0.f, 0.f};
  f32x4 acc[8] = {zero, zero, zero, zero, zero, zero, zero, zero};
  for (int kb = 0; kb < 128; kb += 32) {
    bf16x8 ah;
    int row = bm + nl;
    if (row < M)
      ah = *(const bf16x8*)(AH + (size_t)row * lda + kb + quad * 8);
    else
#pragma unroll
      for (int j = 0; j < 8; ++j) ah[j] = 0;
#pragma unroll
    for (int tn = 0; tn < 8; ++tn) {
      const unsigned short* BH = (tn < 4) ? B1H : B2H;
      const unsigned short* BL = (tn < 4) ? B1L : B2L;
      size_t boff = (size_t)(yp * 64 + (tn & 3) * 16 + nl) * 128 + kb + quad * 8;
      bf16x8 bh = *(const bf16x8*)(BH + boff);
      bf16x8 bl = *(const bf16x8*)(BL + boff);
      acc[tn] = mfma16(ah, bh, acc[tn]);
      acc[tn] = mfma16(ah, bl, acc[tn]);
    }
  }
#pragma unroll
  for (int tn = 0; tn < 8; ++tn) {
    int cc = yp * 64 + (tn & 3) * 16 + nl;
    float bv = (tn < 4 && cc < 642) ? bias1[cc] : 0.f;
    unsigned short* CP = (tn < 4) ? C1 : C2;
#pragma unroll
    for (int r = 0; r < 4; ++r) {
      int rr = bm + quad * 4 + r;
      if (rr >= M) continue;
      CP[(size_t)yp * planeN + (size_t)rr * 64 + (tn & 3) * 16 + nl] =
          f2bf(acc[tn][r] + bv);
    }
  }
}

// --- fused edge kernel: depth-2 gather pipeline, drain-free weight ordering
__global__ __launch_bounds__(256, 3) void k_edge_mfma(
    const unsigned short* __restrict__ Ap, const unsigned short* __restrict__ Bp,
    int planeN,
    const int* __restrict__ ssrc, const int* __restrict__ sdst,
    const float* __restrict__ sd_g, int E,
    const unsigned short* __restrict__ WeaT,  // [704][64] bf16
    const float* __restrict__ Wea64,          // [642] fp32 (d-row of W1)
    const unsigned short* __restrict__ W2T,   // [32][704] bf16
    const float* __restrict__ b2v,
    const float* __restrict__ eng, const float* __restrict__ enb,
    float* __restrict__ msum) {
  __shared__ float sAB[4][16 * 68];           // wave-owned staging (fp32)
  __shared__ unsigned short sHh[4][16 * 72];  // wave-owned h tile (bf16)
  __shared__ float sDs[64];
  __shared__ int sSrcS[64], sDstS[64];

  const int t = threadIdx.x;
  const int wave = t >> 6, lane = t & 63;
  const int nl = lane & 15, quad = lane >> 4;
  const int e0 = blockIdx.x * 64;

  if (lane < 16) {
    int el = wave * 16 + lane;
    int e = e0 + el;
    int ec = (e < E) ? e : (E - 1);
    sSrcS[el] = ssrc[ec];
    sDstS[el] = sdst[ec];
    sDs[el] = sd_g[ec];
  }
  const int r = lane >> 2, cq = lane & 3;
  const int elr = wave * 16 + r;
  const size_t aOff = (size_t)sDstS[elr] * 64 + cq * 16;
  const size_t bOff = (size_t)sSrcS[elr] * 64 + cq * 16;
  const float dR = sDs[elr];
  float* myAB = sAB[wave];
  unsigned short* myH = sHh[wave];

  bf16x8 pa0[2], pa1[2], pb0[2], pb1[2];  // depth-2 staging slots
  bf16x8 w1[4][2], w2[2][2][2];           // w2[buf][tn][ks]

  auto loadW1 = [&](int c) {
#pragma unroll
    for (int tn = 0; tn < 4; ++tn)
#pragma unroll
      for (int ks = 0; ks < 2; ++ks)
        w1[tn][ks] = *(const bf16x8*)(WeaT + (size_t)(c * 64 + tn * 16 + nl) * 64 +
                                      ks * 32 + quad * 8);
  };
  auto loadW2 = [&](int c, int buf) {
#pragma unroll
    for (int tn = 0; tn < 2; ++tn)
#pragma unroll
      for (int ks = 0; ks < 2; ++ks)
        w2[buf][tn][ks] = *(const bf16x8*)(W2T + (size_t)(tn * 16 + nl) * 704 +
                                           c * 64 + ks * 32 + quad * 8);
  };
  auto issue = [&](int c, int s) {
    const unsigned short* a = Ap + (size_t)c * planeN + aOff;
    const unsigned short* b = Bp + (size_t)c * planeN + bOff;
    pa0[s] = *(const bf16x8*)a;
    pa1[s] = *(const bf16x8*)(a + 8);
    pb0[s] = *(const bf16x8*)b;
    pb1[s] = *(const bf16x8*)(b + 8);
  };
  auto commit = [&](int c, int s) {
    float za[16], zb[16], w[16];
    unpack8(pa0[s], za); unpack8(pa1[s], za + 8);
    unpack8(pb0[s], zb); unpack8(pb1[s], zb + 8);
    const int cb = c * 64 + cq * 16;
    if (cb + 15 < 642) {
#pragma unroll
      for (int j = 0; j < 4; ++j) {
        f32x4 wv = *(const f32x4*)(Wea64 + cb + 4 * j);
        w[4 * j] = wv.x; w[4 * j + 1] = wv.y; w[4 * j + 2] = wv.z; w[4 * j + 3] = wv.w;
      }
    } else {
#pragma unroll
      for (int u = 0; u < 16; ++u) w[u] = (cb + u < 642) ? Wea64[cb + u] : 0.f;
    }
#pragma unroll
    for (int j = 0; j < 4; ++j) {
      f32x4 o;
#pragma unroll
      for (int u = 0; u < 4; ++u) o[u] = za[4 * j + u] + zb[4 * j + u] + dR * w[4 * j + u];
      *(f32x4*)(myAB + r * 68 + cq * 16 + 4 * j) = o;
    }
  };

  issue(0, 0);  // oldest in flight
  bf16x8 eaHi[2];
  {
    float d = sDs[wave * 16 + nl];
#pragma unroll
    for (int ks = 0; ks < 2; ++ks)
#pragma unroll
      for (int j = 0; j < 8; ++j) {
        int k = ks * 32 + quad * 8 + j;
        float arg = d * exp2f(-(float)(k & 31));
        float v = (k < 32) ? __sinf(arg) : __cosf(arg);
        eaHi[ks][j] = (short)f2bf(v);
      }
  }
  loadW1(0);
  loadW2(0, 0);
  loadW2(1, 1);
  issue(1, 1);  // depth-2: second chunk in flight

  f32x4 zero = {0.f, 0.f, 0.f, 0.f};
  f32x4 macc[2] = {zero, zero};

#pragma unroll
  for (int c = 0; c < 11; ++c) {
    commit(c, c & 1);  // ONLY gather wait; 2 chunks of cover
    // GEMM1 (zero-seeded; staged add after, overlapping MFMA latency)
    f32x4 acc1[4] = {zero, zero, zero, zero};
#pragma unroll
    for (int tn = 0; tn < 4; ++tn)
#pragma unroll
      for (int ks = 0; ks < 2; ++ks) acc1[tn] = mfma16(eaHi[ks], w1[tn][ks], acc1[tn]);
#pragma unroll
    for (int tn = 0; tn < 4; ++tn)
#pragma unroll
      for (int rr = 0; rr < 4; ++rr) {
        int lrow = quad * 4 + rr;
        float z = acc1[tn][rr] + myAB[lrow * 68 + tn * 16 + nl];
        myH[lrow * 72 + tn * 16 + nl] = f2bf(siluf(z));
      }
    if (c < 10) loadW1(c + 1);  // w1 free after gemm1
    // GEMM2: h (bf16, wave-owned rows) @ W2 chunk — w2(c) drained at commit
#pragma unroll
    for (int ks = 0; ks < 2; ++ks) {
      bf16x8 ah = *(const bf16x8*)(myH + nl * 72 + ks * 32 + quad * 8);
#pragma unroll
      for (int tn = 0; tn < 2; ++tn) macc[tn] = mfma16(ah, w2[c & 1][tn][ks], macc[tn]);
    }
    if (c < 9) {
      loadW2(c + 2, c & 1);  // buf freed by gemm2 above
      issue(c + 2, c & 1);   // slot freed by commit above
    }
  }

  // epilogue: bias+silu+LN(32) via width-16 shuffles -> sM (fp32, in sAB)
  float g0 = eng[nl], g1v = eng[16 + nl], bb0 = enb[nl], bb1 = enb[16 + nl];
  float bi0 = b2v[nl], bi1 = b2v[16 + nl];
  float* sMw = myAB;  // rows 0..15 stride 33
#pragma unroll
  for (int rr = 0; rr < 4; ++rr) {
    float v0 = siluf(macc[0][rr] + bi0);
    float v1 = siluf(macc[1][rr] + bi1);
    float s = v0 + v1;
    float ss = v0 * v0 + v1 * v1;
#pragma unroll
    for (int m = 1; m < 16; m <<= 1) {
      s += __shfl_xor(s, m, 16);
      ss += __shfl_xor(ss, m, 16);
    }
    float mu = s * (1.f / 32.f);
    float var = ss * (1.f / 32.f) - mu * mu;
    float rs = rsqrtf(var + 1e-5f);
    int lr = quad * 4 + rr;
    sMw[lr * 33 + nl] = (v0 - mu) * rs * g0 + bb0;
    sMw[lr * 33 + 16 + nl] = (v1 - mu) * rs * g1v + bb1;
  }
  __syncthreads();  // only barrier: cross-wave sM/sDstS visibility
  {
    int col = t & 31, seg = t >> 5;
    float acc = 0.f;
    int cur = -1;
#pragma unroll
    for (int i = 0; i < 8; ++i) {
      int e = seg * 8 + i;
      int dn = (e0 + e < E) ? sDstS[e] : -1;
      if (dn != cur) {
        if (cur >= 0) atomicAdd(&msum[(size_t)cur * 32 + col], acc);
        acc = 0.f;
        cur = dn;
      }
      if (dn >= 0) acc += sAB[e >> 4][(e & 15) * 33 + col];
    }
    if (cur >= 0) atomicAdd(&msum[(size_t)cur * 32 + col], acc);
  }
}

// ------------------------------- node-side LN + concat builder (bf16 out)
__global__ __launch_bounds__(256) void k_node_ln(
    const float* __restrict__ msum, const float* __restrict__ deg,
    const float* __restrict__ featsAll, int k,
    const float* __restrict__ n1g, const float* __restrict__ n1b,
    const float* __restrict__ eng, const float* __restrict__ enb,
    unsigned short* __restrict__ hcatH, int N) {
  int node = blockIdx.x * 4 + (threadIdx.x >> 6);
  int lane = threadIdx.x & 63;
  if (node >= N) return;
  const float* fr = featsAll + (size_t)node * 768 + k * 128;
  float x0 = fr[lane], x1 = fr[64 + lane];
  float s = x0 + x1;
#pragma unroll
  for (int m = 1; m < 64; m <<= 1) s += __shfl_xor(s, m, 64);
  float mu = s * (1.f / 128.f);
  float d0 = x0 - mu, d1 = x1 - mu;
  float v = d0 * d0 + d1 * d1;
#pragma unroll
  for (int m = 1; m < 64; m <<= 1) v += __shfl_xor(v, m, 64);
  float rstd = rsqrtf(v * (1.f / 128.f) + 1e-5f);
  size_t hb = (size_t)node * 160;
  hcatH[hb + lane] = f2bf(d0 * rstd * n1g[lane] + n1b[lane]);
  hcatH[hb + 64 + lane] = f2bf(d1 * rstd * n1g[64 + lane] + n1b[64 + lane]);
  float dg = deg[node];
  int col = lane & 31;
  float y = msum[(size_t)node * 32 + col] / dg;
  float sy = y;
#pragma unroll
  for (int m = 1; m < 32; m <<= 1) sy += __shfl_xor(sy, m, 32);
  float mu2 = sy * (1.f / 32.f);
  float dy = y - mu2;
  float vy = dy * dy;
#pragma unroll
  for (int m = 1; m < 32; m <<= 1) vy += __shfl_xor(vy, m, 32);
  float rstd2 = rsqrtf(vy * (1.f / 32.f) + 1e-5f);
  if (lane < 32) hcatH[hb + 128 + col] = f2bf(dy * rstd2 * eng[col] + enb[col]);
}

// ------------- fused n2 GEMM + LayerNorm + residual (block = 64 rows x 128)
__global__ __launch_bounds__(256) void k_n2_resid(
    const unsigned short* __restrict__ t1H,
    const unsigned short* __restrict__ BH, const unsigned short* __restrict__ BL,
    const float* __restrict__ b2,
    const float* __restrict__ n2g, const float* __restrict__ n2b,
    float* __restrict__ featsAll, unsigned short* __restrict__ fH, int k, int N) {
  const int t = threadIdx.x;
  const int wave = t >> 6, lane = t & 63;
  const int nl = lane & 15, quad = lane >> 4;
  const int bm = blockIdx.x * 64 + wave * 16;
  f32x4 zero = {0.f, 0.f, 0.f, 0.f};
  f32x4 acc[8] = {zero, zero, zero, zero, zero, zero, zero, zero};
  for (int kb = 0; kb < 256; kb += 32) {
    bf16x8 ah;
    int row = bm + nl;
    if (row < N)
      ah = *(const bf16x8*)(t1H + (size_t)row * 256 + kb + quad * 8);
    else
#pragma unroll
      for (int j = 0; j < 8; ++j) ah[j] = 0;
#pragma unroll
    for (int tn = 0; tn < 8; ++tn) {
      size_t boff = (size_t)(tn * 16 + nl) * 256 + kb + quad * 8;
      bf16x8 bh = *(const bf16x8*)(BH + boff);
      bf16x8 bl = *(const bf16x8*)(BL + boff);
      acc[tn] = mfma16(ah, bh, acc[tn]);
      acc[tn] = mfma16(ah, bl, acc[tn]);
    }
  }
  float bv[8], gv[8], bb[8];
#pragma unroll
  for (int tn = 0; tn < 8; ++tn) {
    int col = tn * 16 + nl;
    bv[tn] = b2[col];
    gv[tn] = n2g[col];
    bb[tn] = n2b[col];
  }
#pragma unroll
  for (int r = 0; r < 4; ++r) {
    int row = bm + quad * 4 + r;
    float v[8];
    float s = 0.f, ss = 0.f;
#pragma unroll
    for (int tn = 0; tn < 8; ++tn) {
      v[tn] = acc[tn][r] + bv[tn];
      s += v[tn];
      ss += v[tn] * v[tn];
    }
#pragma unroll
    for (int m = 1; m < 16; m <<= 1) {
      s += __shfl_xor(s, m, 16);
      ss += __shfl_xor(ss, m, 16);
    }
    float mu = s * (1.f / 128.f);
    float var = ss * (1.f / 128.f) - mu * mu;
    float rs = rsqrtf(var + 1e-5f);
    if (row < N) {
      const float* fk = featsAll + (size_t)row * 768 + k * 128;
      size_t ob = (size_t)row * 768 + (k + 1) * 128;
#pragma unroll
      for (int tn = 0; tn < 8; ++tn) {
        int col = tn * 16 + nl;
        float o = fk[col] + (v[tn] - mu) * rs * gv[tn] + bb[tn];
        featsAll[ob + col] = o;
        fH[ob + col] = f2bf(o);
      }
    }
  }
}

// ------------------------------------- graph pooling (batch sorted -> runs)
__global__ __launch_bounds__(256) void k_pool2(const float* __restrict__ f,
                                               const int* __restrict__ batch,
                                               float* __restrict__ gsum,
                                               float* __restrict__ gcnt, int N) {
  int n0 = blockIdx.x * 64;
  int col = threadIdx.x;
  float acc = 0.f;
  int cur = -1;
  for (int i = 0; i < 64; ++i) {
    int n = n0 + i;
    if (n >= N) break;
    int b = batch[n];
    if (b != cur) {
      if (cur >= 0) atomicAdd(&gsum[cur * 256 + col], acc);
      acc = 0.f;
      cur = b;
    }
    acc += f[(size_t)n * 256 + col];
  }
  if (cur >= 0) atomicAdd(&gsum[cur * 256 + col], acc);
  if (threadIdx.x == 0) {
    int cnt = 0;
    cur = -1;
    for (int i = 0; i < 64; ++i) {
      int n = n0 + i;
      if (n >= N) break;
      int b = batch[n];
      if (b != cur) {
        if (cur >= 0) atomicAdd(&gcnt[cur], (float)cnt);
        cnt = 0;
        cur = b;
      }
      cnt++;
    }
    if (cur >= 0) atomicAdd(&gcnt[cur], (float)cnt);
  }
}

__global__ void k_gdiv(float* gsum, const float* gcnt, unsigned short* gH) {
  int b = blockIdx.x, j = threadIdx.x;
  float v = gsum[b * 256 + j] / fmaxf(gcnt[b], 1.f);
  gH[b * 256 + j] = f2bf(v);
}

__global__ void k_gout(const float* __restrict__ g2, const float* __restrict__ gW2,
                       const float* __restrict__ gb2, float* __restrict__ out) {
  int b = threadIdx.x;
  if (b >= 64) return;
  float s = gb2[0];
  for (int j = 0; j < 256; ++j) s += g2[b * 256 + j] * gW2[j];
  out[b] = s;
}

// ------------------------------------------------------------------- launch
extern "C" void kernel_launch(void* const* d_in, const int* in_sizes, int n_in,
                              void* d_out, int out_size, void* d_ws, size_t ws_size,
                              hipStream_t stream) {
  const float* coords = (const float*)d_in[0];
  const int* atomids = (const int*)d_in[1];
  const int* ei = (const int*)d_in[2];
  const int* batch = (const int*)d_in[3];
  const float* emb = (const float*)d_in[5];
  const float* keW1 = (const float*)d_in[6];
  const float* keb1 = (const float*)d_in[7];
  const float* keW2 = (const float*)d_in[8];
  const float* keb2 = (const float*)d_in[9];
  const float* keng = (const float*)d_in[10];
  const float* kenb = (const float*)d_in[11];
  const float* kn1g = (const float*)d_in[12];
  const float* kn1b = (const float*)d_in[13];
  const float* knW1 = (const float*)d_in[14];
  const float* knb1 = (const float*)d_in[15];
  const float* knW2 = (const float*)d_in[16];
  const float* knb2 = (const float*)d_in[17];
  const float* kn2g = (const float*)d_in[18];
  const float* kn2b = (const float*)d_in[19];
  const float* fW0 = (const float*)d_in[20];
  const float* fb0 = (const float*)d_in[21];
  const float* fW1 = (const float*)d_in[22];
  const float* fb1 = (const float*)d_in[23];
  const float* fW2 = (const float*)d_in[24];
  const float* fb2 = (const float*)d_in[25];
  const float* gW0 = (const float*)d_in[26];
  const float* gb0 = (const float*)d_in[27];
  const float* gW1 = (const float*)d_in[28];
  const float* gb1 = (const float*)d_in[29];
  const float* gW2 = (const float*)d_in[30];
  const float* gb2 = (const float*)d_in[31];

  const int N = in_sizes[0] / 3;
  const int E = in_sizes[2] / 2;
  const int planeN = N * 64;

  size_t off = 0;
  auto alloc = [&](size_t n) {
    float* p = (float*)d_ws + off;
    off += (n + 63) & ~(size_t)63;
    return p;
  };
  float* feats_all = alloc((size_t)N * 768);
  float* d_arr = alloc(E);
  float* degf = alloc(N);
  float* msum = alloc((size_t)N * 32);
  float* f1 = alloc((size_t)N * 256);
  float* gsum = alloc(64 * 256);
  float* gcnt = alloc(64);
  float* g2 = alloc(64 * 256);
  int* cnt = (int*)alloc(N);
  int* cursor = (int*)alloc(N);
  int* ssrc = (int*)alloc(E);
  int* sdst = (int*)alloc(E);
  float* sd = alloc(E);

  unsigned short* ubase = (unsigned short*)(alloc(0));
  size_t uoff = 0;
  auto ualloc = [&](size_t n) {
    unsigned short* p = ubase + uoff;
    uoff += (n + 63) & ~(size_t)63;
    return p;
  };
  unsigned short* fH = ualloc((size_t)N * 768);
  unsigned short* ApU = ualloc((size_t)11 * planeN);
  unsigned short* BpU = ualloc((size_t)11 * planeN);
  unsigned short* hcatH = ualloc((size_t)N * 160);
  unsigned short* t1H = ualloc((size_t)N * 256);
  unsigned short* fAH = ualloc((size_t)N * 256);
  unsigned short* fBH = ualloc((size_t)N * 256);
  unsigned short* gH = ualloc(64 * 256);
  unsigned short* g1H = ualloc(64 * 256);
  const size_t sDst_ = 704 * 128, sSrc_ = 704 * 128, sEa_ = 704 * 64;
  const size_t sW2_ = 32 * 704, sN1_ = 256 * 160, sN2_ = 128 * 256;
  unsigned short* PdstH = ualloc(5 * sDst_); unsigned short* PdstL = ualloc(5 * sDst_);
  unsigned short* PsrcH = ualloc(5 * sSrc_); unsigned short* PsrcL = ualloc(5 * sSrc_);
  unsigned short* PeaH = ualloc(5 * sEa_);   unsigned short* PeaL = ualloc(5 * sEa_);
  unsigned short* PW2H = ualloc(5 * sW2_);   unsigned short* PW2L = ualloc(5 * sW2_);
  unsigned short* Pn1H = ualloc(5 * sN1_);   unsigned short* Pn1L = ualloc(5 * sN1_);
  unsigned short* Pn2H = ualloc(5 * sN2_);   unsigned short* Pn2L = ualloc(5 * sN2_);
  unsigned short* Pf0H = ualloc(256 * 768);  unsigned short* Pf0L = ualloc(256 * 768);
  unsigned short* Pf1H = ualloc(256 * 256);  unsigned short* Pf1L = ualloc(256 * 256);
  unsigned short* Pf2H = ualloc(256 * 256);  unsigned short* Pf2L = ualloc(256 * 256);
  unsigned short* Pg0H = ualloc(256 * 256);  unsigned short* Pg0L = ualloc(256 * 256);
  unsigned short* Pg1H = ualloc(256 * 256);  unsigned short* Pg1L = ualloc(256 * 256);

  PPJobs jobs;
  auto setJob = [&](int i, const float* W, size_t wStr, int ldw, int K, int Kpad,
                    int Nc, int Npad, unsigned short* hi, unsigned short* lo,
                    size_t oStr, int layers) {
    jobs.j[i] = PPJob{W, hi, lo, (unsigned long long)wStr, (unsigned long long)oStr,
                      ldw, K, Kpad, Nc, Npad, layers};
  };
  setJob(0, keW1, (size_t)321 * 642, 642, 128, 128, 642, 704, PdstH, PdstL, sDst_, 5);
  setJob(1, keW1 + 128 * 642, (size_t)321 * 642, 642, 128, 128, 642, 704, PsrcH, PsrcL, sSrc_, 5);
  setJob(2, keW1 + 256 * 642, (size_t)321 * 642, 642, 64, 64, 642, 704, PeaH, PeaL, sEa_, 5);
  setJob(3, keW2, (size_t)642 * 32, 32, 642, 704, 32, 32, PW2H, PW2L, sW2_, 5);
  setJob(4, knW1, (size_t)160 * 256, 256, 160, 160, 256, 256, Pn1H, Pn1L, sN1_, 5);
  setJob(5, knW2, (size_t)256 * 128, 128, 256, 256, 128, 128, Pn2H, Pn2L, sN2_, 5);
  setJob(6, fW0, 0, 256, 768, 768, 256, 256, Pf0H, Pf0L, 0, 1);
  setJob(7, fW1, 0, 256, 256, 256, 256, 256, Pf1H, Pf1L, 0, 1);
  setJob(8, fW2, 0, 256, 256, 256, 256, 256, Pf2H, Pf2L, 0, 1);
  setJob(9, gW0, 0, 256, 256, 256, 256, 256, Pg0H, Pg0L, 0, 1);
  setJob(10, gW1, 0, 256, 256, 256, 256, 256, Pg1H, Pg1L, 0, 1);
  k_prepack_all<<<dim3(1760, 11), 256, 0, stream>>>(jobs);

  k_gather<<<(N * 128 + 255) / 256, 256, 0, stream>>>(atomids, emb, feats_all, fH, N);
  hipMemsetAsync(cnt, 0, (size_t)N * sizeof(int), stream);
  k_edge_prep<<<(E + 255) / 256, 256, 0, stream>>>(coords, ei, E, d_arr, cnt);
  k_scan2<<<1, 1024, 0, stream>>>(cnt, N, cursor, degf);
  k_scatter<<<(E + 255) / 256, 256, 0, stream>>>(ei, E, d_arr, cursor, ssrc, sdst, sd);

  const int MT64 = (N + 63) / 64;
  for (int k = 0; k < 5; ++k) {
    hipMemsetAsync(msum, 0, (size_t)N * 32 * sizeof(float), stream);
    gemm_proj<<<dim3(MT64, 11), 256, 0, stream>>>(
        fH + k * 128, 768,
        PdstH + k * sDst_, PdstL + k * sDst_,
        PsrcH + k * sSrc_, PsrcL + k * sSrc_,
        keb1 + k * 642, ApU, BpU, planeN, N);
    k_edge_mfma<<<(E + 63) / 64, 256, 0, stream>>>(
        ApU, BpU, planeN, ssrc, sdst, sd, E,
        PeaH + k * sEa_,
        keW1 + (size_t)k * 321 * 642 + (size_t)320 * 642,
        PW2H + k * sW2_,
        keb2 + k * 32, keng + k * 32, kenb + k * 32, msum);
    k_node_ln<<<(N + 3) / 4, 256, 0, stream>>>(
        msum, degf, feats_all, k, kn1g + k * 128, kn1b + k * 128,
        keng + k * 32, kenb + k * 32, hcatH, N);
    gemm_bf<<<dim3(MT64, 4), 256, 0, stream>>>(
        hcatH, 160, Pn1H + k * sN1_, Pn1L + k * sN1_, 160,
        knb1 + k * 256, nullptr, 0, t1H, 256, N, 256, 160, 1, 0);
    k_n2_resid<<<MT64, 256, 0, stream>>>(
        t1H, Pn2H + k * sN2_, Pn2L + k * sN2_, knb2 + k * 128,
        kn2g + k * 128, kn2b + k * 128, feats_all, fH, k, N);
  }

  gemm_bf<<<dim3(MT64, 4), 256, 0, stream>>>(
      fH, 768, Pf0H, Pf0L, 768, fb0, nullptr, 0, fAH, 256, N, 256, 768, 1, 1);
  gemm_bf<<<dim3(MT64, 4), 256, 0, stream>>>(
      fAH, 256, Pf1H, Pf1L, 256, fb1, nullptr, 0, fBH, 256, N, 256, 256, 1, 0);
  gemm_bf<<<dim3(MT64, 4), 256, 0, stream>>>(
      fBH, 256, Pf2H, Pf2L, 256, fb2, f1, 256, nullptr, 0, N, 256, 256, 1, 0);

  hipMemsetAsync(gsum, 0, 64 * 256 * sizeof(float), stream);
  hipMemsetAsync(gcnt, 0, 64 * sizeof(float), stream);
  k_pool2<<<(N + 63) / 64, 256, 0, stream>>>(f1, batch, gsum, gcnt, N);
  k_gdiv<<<64, 256, 0, stream>>>(gsum, gcnt, gH);
  gemm_bf<<<dim3(1, 4), 256, 0, stream>>>(
      gH, 256, Pg0H, Pg0L, 256, gb0, nullptr, 0, g1H, 256, 64, 256, 256, 1, 0);
  gemm_bf<<<dim3(1, 4), 256, 0, stream>>>(
      g1H, 256, Pg1H, Pg1L, 256, gb1, g2, 256, nullptr, 0, 64, 256, 256, 1, 0);
  k_gout<<<1, 64, 0, stream>>>(g2, gW2, gb2, (float*)d_out);
}

// Round 10
// 1819.670 us; speedup vs baseline: 1.0382x; 1.0382x over previous
//
#include <hip/hip_runtime.h>
#include <cstdint>
#include <cstddef>

// DeltaNetMolecular R10: R9 depth-2 edge kernel but launch_bounds(256,5) -->
// 5 blocks/CU (LDS 27.6KB allows it; was self-capped at 3). gemm_proj reverted
// to R8's faster M=128/y=22 form. Everything else unchanged.

#define DEV __device__ __forceinline__

typedef __attribute__((ext_vector_type(8))) short bf16x8;
typedef __attribute__((ext_vector_type(4))) float f32x4;

DEV float siluf(float x) { return x / (1.f + __expf(-x)); }

DEV unsigned short f2bf(float f) {
  unsigned u = __float_as_uint(f);
  unsigned r = u + 0x7FFFu + ((u >> 16) & 1u);
  return (unsigned short)(r >> 16);
}
DEV float bf2f(unsigned short h) { return __uint_as_float(((unsigned)h) << 16); }

DEV f32x4 mfma16(bf16x8 a, bf16x8 b, f32x4 c) {
  return __builtin_amdgcn_mfma_f32_16x16x32_bf16(a, b, c, 0, 0, 0);
}

DEV void unpack8(bf16x8 v, float* o) {
#pragma unroll
  for (int j = 0; j < 8; ++j) o[j] = bf2f((unsigned short)v[j]);
}

// ------------------------------------------------- gather emb (+bf16 copy)
__global__ __launch_bounds__(256) void k_gather(const int* __restrict__ atomids,
                                                const float* __restrict__ emb,
                                                float* __restrict__ feats_all,
                                                unsigned short* __restrict__ fH, int N) {
  int idx = blockIdx.x * 256 + threadIdx.x;
  if (idx >= N * 128) return;
  int i = idx >> 7, j = idx & 127;
  float v = emb[atomids[i] * 128 + j];
  size_t o = (size_t)i * 768 + j;
  feats_all[o] = v;
  fH[o] = f2bf(v);
}

// --------------------------------------------------- edge dist + dst histogram
__global__ __launch_bounds__(256) void k_edge_prep(const float* __restrict__ coords,
                                                   const int* __restrict__ ei, int E,
                                                   float* __restrict__ d_arr,
                                                   int* __restrict__ cnt) {
  int e = blockIdx.x * 256 + threadIdx.x;
  if (e >= E) return;
  int s = ei[e], t = ei[E + e];
  float dx = coords[3 * s + 0] - coords[3 * t + 0];
  float dy = coords[3 * s + 1] - coords[3 * t + 1];
  float dz = coords[3 * s + 2] - coords[3 * t + 2];
  d_arr[e] = dx * dx + dy * dy + dz * dz;
  atomicAdd(&cnt[t], 1);
}

// -------------------- single-block scan, shuffle-based (2 barriers total)
__global__ __launch_bounds__(1024) void k_scan2(const int* __restrict__ cnt, int N,
                                                int* __restrict__ cursor,
                                                float* __restrict__ degf) {
  __shared__ int wsum[16];
  int tid = threadIdx.x;
  int chunk = (N + 1023) >> 10;
  int lo = tid * chunk, hi = min(N, lo + chunk);
  int s = 0;
  for (int i = lo; i < hi; ++i) s += cnt[i];
  int lane = tid & 63, wv = tid >> 6;
  int v = s;
#pragma unroll
  for (int off = 1; off < 64; off <<= 1) {
    int u = __shfl_up(v, off, 64);
    if (lane >= off) v += u;
  }
  if (lane == 63) wsum[wv] = v;
  __syncthreads();
  if (wv == 0 && lane < 16) {
    int w = wsum[lane];
#pragma unroll
    for (int off = 1; off < 16; off <<= 1) {
      int u = __shfl_up(w, off, 16);
      if (lane >= off) w += u;
    }
    wsum[lane] = w;
  }
  __syncthreads();
  int run = (wv ? wsum[wv - 1] : 0) + v - s;  // exclusive prefix
  for (int i = lo; i < hi; ++i) {
    int c = cnt[i];
    cursor[i] = run;
    degf[i] = fmaxf((float)c, 1.f);
    run += c;
  }
}

// ------------------------------------------------------- scatter sorted edges
__global__ __launch_bounds__(256) void k_scatter(const int* __restrict__ ei, int E,
                                                 const float* __restrict__ d_arr,
                                                 int* __restrict__ cursor,
                                                 int* __restrict__ ssrc,
                                                 int* __restrict__ sdst,
                                                 float* __restrict__ sd) {
  int e = blockIdx.x * 256 + threadIdx.x;
  if (e >= E) return;
  int s = ei[e], t = ei[E + e];
  int p = atomicAdd(&cursor[t], 1);
  ssrc[p] = s;
  sdst[p] = t;
  sd[p] = d_arr[e];
}

// ------------------------------------ merged weight prepack (one launch)
struct PPJob {
  const float* W;
  unsigned short* hi;
  unsigned short* lo;
  unsigned long long wStride, oStride;
  int ldw, K, Kpad, Nc, Npad, layers;
};
struct PPJobs { PPJob j[11]; };

__global__ __launch_bounds__(256) void k_prepack_all(PPJobs jobs) {
  PPJob jb = jobs.j[blockIdx.y];
  long long per = (long long)jb.Npad * jb.Kpad;
  long long idx = (long long)blockIdx.x * 256 + threadIdx.x;
  if (idx >= per * jb.layers) return;
  int layer = (int)(idx / per);
  int r = (int)(idx - (long long)layer * per);
  const float* W = jb.W + (size_t)layer * jb.wStride;
  int n = r / jb.Kpad, k = r - n * jb.Kpad;
  float v = (n < jb.Nc && k < jb.K) ? W[(size_t)k * jb.ldw + n] : 0.f;
  unsigned short h = f2bf(v);
  jb.hi[(size_t)layer * jb.oStride + r] = h;
  jb.lo[(size_t)layer * jb.oStride + r] = f2bf(v - bf2f(h));
}

// --------- bf16 MFMA GEMM: A bf16, B hi/lo x2, M=64 per block (grid-rich)
__global__ __launch_bounds__(256) void gemm_bf(
    const unsigned short* __restrict__ AH, int lda,
    const unsigned short* __restrict__ BH, const unsigned short* __restrict__ BL, int ldb,
    const float* __restrict__ bias,
    float* __restrict__ C, int ldc,
    unsigned short* __restrict__ CH, int ldch,
    int M, int Ncols, int K, int actOut, int actA) {
  const int t = threadIdx.x;
  const int wave = t >> 6, lane = t & 63;
  const int nl = lane & 15, quad = lane >> 4;
  const int bm = blockIdx.x * 64 + wave * 16;
  const int bn = blockIdx.y * 64;
  f32x4 zero = {0.f, 0.f, 0.f, 0.f};
  f32x4 acc[4] = {zero, zero, zero, zero};
  for (int kb = 0; kb < K; kb += 32) {
    bf16x8 ah;
    int row = bm + nl;
    if (row < M) {
      ah = *(const bf16x8*)(AH + (size_t)row * lda + kb + quad * 8);
      if (actA) {
#pragma unroll
        for (int j = 0; j < 8; ++j)
          ah[j] = (short)f2bf(siluf(bf2f((unsigned short)ah[j])));
      }
    } else {
#pragma unroll
      for (int j = 0; j < 8; ++j) ah[j] = 0;
    }
#pragma unroll
    for (int tn = 0; tn < 4; ++tn) {
      size_t boff = (size_t)(bn + tn * 16 + nl) * ldb + kb + quad * 8;
      bf16x8 bh = *(const bf16x8*)(BH + boff);
      bf16x8 bl = *(const bf16x8*)(BL + boff);
      acc[tn] = mfma16(ah, bh, acc[tn]);
      acc[tn] = mfma16(ah, bl, acc[tn]);
    }
  }
#pragma unroll
  for (int tn = 0; tn < 4; ++tn) {
    int c = bn + tn * 16 + nl;
    float bv = (bias && c < Ncols) ? bias[c] : 0.f;
#pragma unroll
    for (int r = 0; r < 4; ++r) {
      int rr = bm + quad * 4 + r;
      if (rr >= M) continue;
      float v = acc[tn][r] + bv;
      if (actOut) v = siluf(v);
      if (C && c < Ncols) C[(size_t)rr * ldc + c] = v;
      if (CH && c < Ncols) CH[(size_t)rr * ldch + c] = f2bf(v);
    }
  }
}

// --------- merged A/B projection GEMM -> bf16 chunk planes (y: 0..21, R8 form)
__global__ __launch_bounds__(256) void gemm_proj(
    const unsigned short* __restrict__ AH, int lda,
    const unsigned short* __restrict__ B1H, const unsigned short* __restrict__ B1L,
    const unsigned short* __restrict__ B2H, const unsigned short* __restrict__ B2L,
    const float* __restrict__ bias1,
    unsigned short* __restrict__ C1, unsigned short* __restrict__ C2,
    int planeN, int M) {
  const int y = blockIdx.y;
  const unsigned short* BH;
  const unsigned short* BL;
  const float* bias;
  unsigned short* CP;
  int yp;
  if (y < 11) { BH = B1H; BL = B1L; bias = bias1; CP = C1; yp = y; }
  else        { BH = B2H; BL = B2L; bias = nullptr; CP = C2; yp = y - 11; }
  const int t = threadIdx.x;
  const int wave = t >> 6, lane = t & 63;
  const int nl = lane & 15, quad = lane >> 4;
  const int bm = blockIdx.x * 128 + wave * 32;
  const int bn = yp * 64;
  f32x4 zero = {0.f, 0.f, 0.f, 0.f};
  f32x4 acc[2][4] = {{zero, zero, zero, zero}, {zero, zero, zero, zero}};
  for (int kb = 0; kb < 128; kb += 32) {
    bf16x8 ah[2];
#pragma unroll
    for (int h = 0; h < 2; ++h) {
      int row = bm + h * 16 + nl;
      if (row < M)
        ah[h] = *(const bf16x8*)(AH + (size_t)row * lda + kb + quad * 8);
      else
#pragma unroll
        for (int j = 0; j < 8; ++j) ah[h][j] = 0;
    }
#pragma unroll
    for (int tn = 0; tn < 4; ++tn) {
      size_t boff = (size_t)(bn + tn * 16 + nl) * 128 + kb + quad * 8;
      bf16x8 bh = *(const bf16x8*)(BH + boff);
      bf16x8 bl = *(const bf16x8*)(BL + boff);
#pragma unroll
      for (int h = 0; h < 2; ++h) {
        acc[h][tn] = mfma16(ah[h], bh, acc[h][tn]);
        acc[h][tn] = mfma16(ah[h], bl, acc[h][tn]);
      }
    }
  }
#pragma unroll
  for (int h = 0; h < 2; ++h) {
#pragma unroll
    for (int tn = 0; tn < 4; ++tn) {
      int c = bn + tn * 16 + nl;
      float bv = (bias && c < 642) ? bias[c] : 0.f;
#pragma unroll
      for (int r = 0; r < 4; ++r) {
        int rr = bm + h * 16 + quad * 4 + r;
        if (rr >= M) continue;
        CP[(size_t)yp * planeN + (size_t)rr * 64 + tn * 16 + nl] =
            f2bf(acc[h][tn][r] + bv);
      }
    }
  }
}

// --- fused edge kernel: depth-2 gather pipeline, 5 blocks/CU occupancy
__global__ __launch_bounds__(256, 5) void k_edge_mfma(
    const unsigned short* __restrict__ Ap, const unsigned short* __restrict__ Bp,
    int planeN,
    const int* __restrict__ ssrc, const int* __restrict__ sdst,
    const float* __restrict__ sd_g, int E,
    const unsigned short* __restrict__ WeaT,  // [704][64] bf16
    const float* __restrict__ Wea64,          // [642] fp32 (d-row of W1)
    const unsigned short* __restrict__ W2T,   // [32][704] bf16
    const float* __restrict__ b2v,
    const float* __restrict__ eng, const float* __restrict__ enb,
    float* __restrict__ msum) {
  __shared__ float sAB[4][16 * 68];           // wave-owned staging (fp32)
  __shared__ unsigned short sHh[4][16 * 72];  // wave-owned h tile (bf16)
  __shared__ float sDs[64];
  __shared__ int sSrcS[64], sDstS[64];

  const int t = threadIdx.x;
  const int wave = t >> 6, lane = t & 63;
  const int nl = lane & 15, quad = lane >> 4;
  const int e0 = blockIdx.x * 64;

  if (lane < 16) {
    int el = wave * 16 + lane;
    int e = e0 + el;
    int ec = (e < E) ? e : (E - 1);
    sSrcS[el] = ssrc[ec];
    sDstS[el] = sdst[ec];
    sDs[el] = sd_g[ec];
  }
  const int r = lane >> 2, cq = lane & 3;
  const int elr = wave * 16 + r;
  const size_t aOff = (size_t)sDstS[elr] * 64 + cq * 16;
  const size_t bOff = (size_t)sSrcS[elr] * 64 + cq * 16;
  const float dR = sDs[elr];
  float* myAB = sAB[wave];
  unsigned short* myH = sHh[wave];

  bf16x8 pa0[2], pa1[2], pb0[2], pb1[2];  // depth-2 staging slots
  bf16x8 w1[4][2], w2[2][2][2];           // w2[buf][tn][ks]

  auto loadW1 = [&](int c) {
#pragma unroll
    for (int tn = 0; tn < 4; ++tn)
#pragma unroll
      for (int ks = 0; ks < 2; ++ks)
        w1[tn][ks] = *(const bf16x8*)(WeaT + (size_t)(c * 64 + tn * 16 + nl) * 64 +
                                      ks * 32 + quad * 8);
  };
  auto loadW2 = [&](int c, int buf) {
#pragma unroll
    for (int tn = 0; tn < 2; ++tn)
#pragma unroll
      for (int ks = 0; ks < 2; ++ks)
        w2[buf][tn][ks] = *(const bf16x8*)(W2T + (size_t)(tn * 16 + nl) * 704 +
                                           c * 64 + ks * 32 + quad * 8);
  };
  auto issue = [&](int c, int s) {
    const unsigned short* a = Ap + (size_t)c * planeN + aOff;
    const unsigned short* b = Bp + (size_t)c * planeN + bOff;
    pa0[s] = *(const bf16x8*)a;
    pa1[s] = *(const bf16x8*)(a + 8);
    pb0[s] = *(const bf16x8*)b;
    pb1[s] = *(const bf16x8*)(b + 8);
  };
  auto commit = [&](int c, int s) {
    float za[16], zb[16], w[16];
    unpack8(pa0[s], za); unpack8(pa1[s], za + 8);
    unpack8(pb0[s], zb); unpack8(pb1[s], zb + 8);
    const int cb = c * 64 + cq * 16;
    if (cb + 15 < 642) {
#pragma unroll
      for (int j = 0; j < 4; ++j) {
        f32x4 wv = *(const f32x4*)(Wea64 + cb + 4 * j);
        w[4 * j] = wv.x; w[4 * j + 1] = wv.y; w[4 * j + 2] = wv.z; w[4 * j + 3] = wv.w;
      }
    } else {
#pragma unroll
      for (int u = 0; u < 16; ++u) w[u] = (cb + u < 642) ? Wea64[cb + u] : 0.f;
    }
#pragma unroll
    for (int j = 0; j < 4; ++j) {
      f32x4 o;
#pragma unroll
      for (int u = 0; u < 4; ++u) o[u] = za[4 * j + u] + zb[4 * j + u] + dR * w[4 * j + u];
      *(f32x4*)(myAB + r * 68 + cq * 16 + 4 * j) = o;
    }
  };

  issue(0, 0);  // oldest in flight
  bf16x8 eaHi[2];
  {
    float d = sDs[wave * 16 + nl];
#pragma unroll
    for (int ks = 0; ks < 2; ++ks)
#pragma unroll
      for (int j = 0; j < 8; ++j) {
        int k = ks * 32 + quad * 8 + j;
        float arg = d * exp2f(-(float)(k & 31));
        float v = (k < 32) ? __sinf(arg) : __cosf(arg);
        eaHi[ks][j] = (short)f2bf(v);
      }
  }
  loadW1(0);
  loadW2(0, 0);
  loadW2(1, 1);
  issue(1, 1);  // depth-2: second chunk in flight

  f32x4 zero = {0.f, 0.f, 0.f, 0.f};
  f32x4 macc[2] = {zero, zero};

#pragma unroll
  for (int c = 0; c < 11; ++c) {
    commit(c, c & 1);  // ONLY gather wait; 2 chunks of cover
    // GEMM1 (zero-seeded; staged add after, overlapping MFMA latency)
    f32x4 acc1[4] = {zero, zero, zero, zero};
#pragma unroll
    for (int tn = 0; tn < 4; ++tn)
#pragma unroll
      for (int ks = 0; ks < 2; ++ks) acc1[tn] = mfma16(eaHi[ks], w1[tn][ks], acc1[tn]);
#pragma unroll
    for (int tn = 0; tn < 4; ++tn)
#pragma unroll
      for (int rr = 0; rr < 4; ++rr) {
        int lrow = quad * 4 + rr;
        float z = acc1[tn][rr] + myAB[lrow * 68 + tn * 16 + nl];
        myH[lrow * 72 + tn * 16 + nl] = f2bf(siluf(z));
      }
    if (c < 10) loadW1(c + 1);  // w1 free after gemm1
    // GEMM2: h (bf16, wave-owned rows) @ W2 chunk — w2(c) drained at commit
#pragma unroll
    for (int ks = 0; ks < 2; ++ks) {
      bf16x8 ah = *(const bf16x8*)(myH + nl * 72 + ks * 32 + quad * 8);
#pragma unroll
      for (int tn = 0; tn < 2; ++tn) macc[tn] = mfma16(ah, w2[c & 1][tn][ks], macc[tn]);
    }
    if (c < 9) {
      loadW2(c + 2, c & 1);  // buf freed by gemm2 above
      issue(c + 2, c & 1);   // slot freed by commit above
    }
  }

  // epilogue: bias+silu+LN(32) via width-16 shuffles -> sM (fp32, in sAB)
  float g0 = eng[nl], g1v = eng[16 + nl], bb0 = enb[nl], bb1 = enb[16 + nl];
  float bi0 = b2v[nl], bi1 = b2v[16 + nl];
  float* sMw = myAB;  // rows 0..15 stride 33
#pragma unroll
  for (int rr = 0; rr < 4; ++rr) {
    float v0 = siluf(macc[0][rr] + bi0);
    float v1 = siluf(macc[1][rr] + bi1);
    float s = v0 + v1;
    float ss = v0 * v0 + v1 * v1;
#pragma unroll
    for (int m = 1; m < 16; m <<= 1) {
      s += __shfl_xor(s, m, 16);
      ss += __shfl_xor(ss, m, 16);
    }
    float mu = s * (1.f / 32.f);
    float var = ss * (1.f / 32.f) - mu * mu;
    float rs = rsqrtf(var + 1e-5f);
    int lr = quad * 4 + rr;
    sMw[lr * 33 + nl] = (v0 - mu) * rs * g0 + bb0;
    sMw[lr * 33 + 16 + nl] = (v1 - mu) * rs * g1v + bb1;
  }
  __syncthreads();  // only barrier: cross-wave sM/sDstS visibility
  {
    int col = t & 31, seg = t >> 5;
    float acc = 0.f;
    int cur = -1;
#pragma unroll
    for (int i = 0; i < 8; ++i) {
      int e = seg * 8 + i;
      int dn = (e0 + e < E) ? sDstS[e] : -1;
      if (dn != cur) {
        if (cur >= 0) atomicAdd(&msum[(size_t)cur * 32 + col], acc);
        acc = 0.f;
        cur = dn;
      }
      if (dn >= 0) acc += sAB[e >> 4][(e & 15) * 33 + col];
    }
    if (cur >= 0) atomicAdd(&msum[(size_t)cur * 32 + col], acc);
  }
}

// ------------------------------- node-side LN + concat builder (bf16 out)
__global__ __launch_bounds__(256) void k_node_ln(
    const float* __restrict__ msum, const float* __restrict__ deg,
    const float* __restrict__ featsAll, int k,
    const float* __restrict__ n1g, const float* __restrict__ n1b,
    const float* __restrict__ eng, const float* __restrict__ enb,
    unsigned short* __restrict__ hcatH, int N) {
  int node = blockIdx.x * 4 + (threadIdx.x >> 6);
  int lane = threadIdx.x & 63;
  if (node >= N) return;
  const float* fr = featsAll + (size_t)node * 768 + k * 128;
  float x0 = fr[lane], x1 = fr[64 + lane];
  float s = x0 + x1;
#pragma unroll
  for (int m = 1; m < 64; m <<= 1) s += __shfl_xor(s, m, 64);
  float mu = s * (1.f / 128.f);
  float d0 = x0 - mu, d1 = x1 - mu;
  float v = d0 * d0 + d1 * d1;
#pragma unroll
  for (int m = 1; m < 64; m <<= 1) v += __shfl_xor(v, m, 64);
  float rstd = rsqrtf(v * (1.f / 128.f) + 1e-5f);
  size_t hb = (size_t)node * 160;
  hcatH[hb + lane] = f2bf(d0 * rstd * n1g[lane] + n1b[lane]);
  hcatH[hb + 64 + lane] = f2bf(d1 * rstd * n1g[64 + lane] + n1b[64 + lane]);
  float dg = deg[node];
  int col = lane & 31;
  float y = msum[(size_t)node * 32 + col] / dg;
  float sy = y;
#pragma unroll
  for (int m = 1; m < 32; m <<= 1) sy += __shfl_xor(sy, m, 32);
  float mu2 = sy * (1.f / 32.f);
  float dy = y - mu2;
  float vy = dy * dy;
#pragma unroll
  for (int m = 1; m < 32; m <<= 1) vy += __shfl_xor(vy, m, 32);
  float rstd2 = rsqrtf(vy * (1.f / 32.f) + 1e-5f);
  if (lane < 32) hcatH[hb + 128 + col] = f2bf(dy * rstd2 * eng[col] + enb[col]);
}

// ------------- fused n2 GEMM + LayerNorm + residual (block = 64 rows x 128)
__global__ __launch_bounds__(256) void k_n2_resid(
    const unsigned short* __restrict__ t1H,
    const unsigned short* __restrict__ BH, const unsigned short* __restrict__ BL,
    const float* __restrict__ b2,
    const float* __restrict__ n2g, const float* __restrict__ n2b,
    float* __restrict__ featsAll, unsigned short* __restrict__ fH, int k, int N) {
  const int t = threadIdx.x;
  const int wave = t >> 6, lane = t & 63;
  const int nl = lane & 15, quad = lane >> 4;
  const int bm = blockIdx.x * 64 + wave * 16;
  f32x4 zero = {0.f, 0.f, 0.f, 0.f};
  f32x4 acc[8] = {zero, zero, zero, zero, zero, zero, zero, zero};
  for (int kb = 0; kb < 256; kb += 32) {
    bf16x8 ah;
    int row = bm + nl;
    if (row < N)
      ah = *(const bf16x8*)(t1H + (size_t)row * 256 + kb + quad * 8);
    else
#pragma unroll
      for (int j = 0; j < 8; ++j) ah[j] = 0;
#pragma unroll
    for (int tn = 0; tn < 8; ++tn) {
      size_t boff = (size_t)(tn * 16 + nl) * 256 + kb + quad * 8;
      bf16x8 bh = *(const bf16x8*)(BH + boff);
      bf16x8 bl = *(const bf16x8*)(BL + boff);
      acc[tn] = mfma16(ah, bh, acc[tn]);
      acc[tn] = mfma16(ah, bl, acc[tn]);
    }
  }
  float bv[8], gv[8], bb[8];
#pragma unroll
  for (int tn = 0; tn < 8; ++tn) {
    int col = tn * 16 + nl;
    bv[tn] = b2[col];
    gv[tn] = n2g[col];
    bb[tn] = n2b[col];
  }
#pragma unroll
  for (int r = 0; r < 4; ++r) {
    int row = bm + quad * 4 + r;
    float v[8];
    float s = 0.f, ss = 0.f;
#pragma unroll
    for (int tn = 0; tn < 8; ++tn) {
      v[tn] = acc[tn][r] + bv[tn];
      s += v[tn];
      ss += v[tn] * v[tn];
    }
#pragma unroll
    for (int m = 1; m < 16; m <<= 1) {
      s += __shfl_xor(s, m, 16);
      ss += __shfl_xor(ss, m, 16);
    }
    float mu = s * (1.f / 128.f);
    float var = ss * (1.f / 128.f) - mu * mu;
    float rs = rsqrtf(var + 1e-5f);
    if (row < N) {
      const float* fk = featsAll + (size_t)row * 768 + k * 128;
      size_t ob = (size_t)row * 768 + (k + 1) * 128;
#pragma unroll
      for (int tn = 0; tn < 8; ++tn) {
        int col = tn * 16 + nl;
        float o = fk[col] + (v[tn] - mu) * rs * gv[tn] + bb[tn];
        featsAll[ob + col] = o;
        fH[ob + col] = f2bf(o);
      }
    }
  }
}

// ------------------------------------- graph pooling (batch sorted -> runs)
__global__ __launch_bounds__(256) void k_pool2(const float* __restrict__ f,
                                               const int* __restrict__ batch,
                                               float* __restrict__ gsum,
                                               float* __restrict__ gcnt, int N) {
  int n0 = blockIdx.x * 64;
  int col = threadIdx.x;
  float acc = 0.f;
  int cur = -1;
  for (int i = 0; i < 64; ++i) {
    int n = n0 + i;
    if (n >= N) break;
    int b = batch[n];
    if (b != cur) {
      if (cur >= 0) atomicAdd(&gsum[cur * 256 + col], acc);
      acc = 0.f;
      cur = b;
    }
    acc += f[(size_t)n * 256 + col];
  }
  if (cur >= 0) atomicAdd(&gsum[cur * 256 + col], acc);
  if (threadIdx.x == 0) {
    int cnt = 0;
    cur = -1;
    for (int i = 0; i < 64; ++i) {
      int n = n0 + i;
      if (n >= N) break;
      int b = batch[n];
      if (b != cur) {
        if (cur >= 0) atomicAdd(&gcnt[cur], (float)cnt);
        cnt = 0;
        cur = b;
      }
      cnt++;
    }
    if (cur >= 0) atomicAdd(&gcnt[cur], (float)cnt);
  }
}

__global__ void k_gdiv(float* gsum, const float* gcnt, unsigned short* gH) {
  int b = blockIdx.x, j = threadIdx.x;
  float v = gsum[b * 256 + j] / fmaxf(gcnt[b], 1.f);
  gH[b * 256 + j] = f2bf(v);
}

__global__ void k_gout(const float* __restrict__ g2, const float* __restrict__ gW2,
                       const float* __restrict__ gb2, float* __restrict__ out) {
  int b = threadIdx.x;
  if (b >= 64) return;
  float s = gb2[0];
  for (int j = 0; j < 256; ++j) s += g2[b * 256 + j] * gW2[j];
  out[b] = s;
}

// ------------------------------------------------------------------- launch
extern "C" void kernel_launch(void* const* d_in, const int* in_sizes, int n_in,
                              void* d_out, int out_size, void* d_ws, size_t ws_size,
                              hipStream_t stream) {
  const float* coords = (const float*)d_in[0];
  const int* atomids = (const int*)d_in[1];
  const int* ei = (const int*)d_in[2];
  const int* batch = (const int*)d_in[3];
  const float* emb = (const float*)d_in[5];
  const float* keW1 = (const float*)d_in[6];
  const float* keb1 = (const float*)d_in[7];
  const float* keW2 = (const float*)d_in[8];
  const float* keb2 = (const float*)d_in[9];
  const float* keng = (const float*)d_in[10];
  const float* kenb = (const float*)d_in[11];
  const float* kn1g = (const float*)d_in[12];
  const float* kn1b = (const float*)d_in[13];
  const float* knW1 = (const float*)d_in[14];
  const float* knb1 = (const float*)d_in[15];
  const float* knW2 = (const float*)d_in[16];
  const float* knb2 = (const float*)d_in[17];
  const float* kn2g = (const float*)d_in[18];
  const float* kn2b = (const float*)d_in[19];
  const float* fW0 = (const float*)d_in[20];
  const float* fb0 = (const float*)d_in[21];
  const float* fW1 = (const float*)d_in[22];
  const float* fb1 = (const float*)d_in[23];
  const float* fW2 = (const float*)d_in[24];
  const float* fb2 = (const float*)d_in[25];
  const float* gW0 = (const float*)d_in[26];
  const float* gb0 = (const float*)d_in[27];
  const float* gW1 = (const float*)d_in[28];
  const float* gb1 = (const float*)d_in[29];
  const float* gW2 = (const float*)d_in[30];
  const float* gb2 = (const float*)d_in[31];

  const int N = in_sizes[0] / 3;
  const int E = in_sizes[2] / 2;
  const int planeN = N * 64;

  size_t off = 0;
  auto alloc = [&](size_t n) {
    float* p = (float*)d_ws + off;
    off += (n + 63) & ~(size_t)63;
    return p;
  };
  float* feats_all = alloc((size_t)N * 768);
  float* d_arr = alloc(E);
  float* degf = alloc(N);
  float* msum = alloc((size_t)N * 32);
  float* f1 = alloc((size_t)N * 256);
  float* gsum = alloc(64 * 256);
  float* gcnt = alloc(64);
  float* g2 = alloc(64 * 256);
  int* cnt = (int*)alloc(N);
  int* cursor = (int*)alloc(N);
  int* ssrc = (int*)alloc(E);
  int* sdst = (int*)alloc(E);
  float* sd = alloc(E);

  unsigned short* ubase = (unsigned short*)(alloc(0));
  size_t uoff = 0;
  auto ualloc = [&](size_t n) {
    unsigned short* p = ubase + uoff;
    uoff += (n + 63) & ~(size_t)63;
    return p;
  };
  unsigned short* fH = ualloc((size_t)N * 768);
  unsigned short* ApU = ualloc((size_t)11 * planeN);
  unsigned short* BpU = ualloc((size_t)11 * planeN);
  unsigned short* hcatH = ualloc((size_t)N * 160);
  unsigned short* t1H = ualloc((size_t)N * 256);
  unsigned short* fAH = ualloc((size_t)N * 256);
  unsigned short* fBH = ualloc((size_t)N * 256);
  unsigned short* gH = ualloc(64 * 256);
  unsigned short* g1H = ualloc(64 * 256);
  const size_t sDst_ = 704 * 128, sSrc_ = 704 * 128, sEa_ = 704 * 64;
  const size_t sW2_ = 32 * 704, sN1_ = 256 * 160, sN2_ = 128 * 256;
  unsigned short* PdstH = ualloc(5 * sDst_); unsigned short* PdstL = ualloc(5 * sDst_);
  unsigned short* PsrcH = ualloc(5 * sSrc_); unsigned short* PsrcL = ualloc(5 * sSrc_);
  unsigned short* PeaH = ualloc(5 * sEa_);   unsigned short* PeaL = ualloc(5 * sEa_);
  unsigned short* PW2H = ualloc(5 * sW2_);   unsigned short* PW2L = ualloc(5 * sW2_);
  unsigned short* Pn1H = ualloc(5 * sN1_);   unsigned short* Pn1L = ualloc(5 * sN1_);
  unsigned short* Pn2H = ualloc(5 * sN2_);   unsigned short* Pn2L = ualloc(5 * sN2_);
  unsigned short* Pf0H = ualloc(256 * 768);  unsigned short* Pf0L = ualloc(256 * 768);
  unsigned short* Pf1H = ualloc(256 * 256);  unsigned short* Pf1L = ualloc(256 * 256);
  unsigned short* Pf2H = ualloc(256 * 256);  unsigned short* Pf2L = ualloc(256 * 256);
  unsigned short* Pg0H = ualloc(256 * 256);  unsigned short* Pg0L = ualloc(256 * 256);
  unsigned short* Pg1H = ualloc(256 * 256);  unsigned short* Pg1L = ualloc(256 * 256);

  PPJobs jobs;
  auto setJob = [&](int i, const float* W, size_t wStr, int ldw, int K, int Kpad,
                    int Nc, int Npad, unsigned short* hi, unsigned short* lo,
                    size_t oStr, int layers) {
    jobs.j[i] = PPJob{W, hi, lo, (unsigned long long)wStr, (unsigned long long)oStr,
                      ldw, K, Kpad, Nc, Npad, layers};
  };
  setJob(0, keW1, (size_t)321 * 642, 642, 128, 128, 642, 704, PdstH, PdstL, sDst_, 5);
  setJob(1, keW1 + 128 * 642, (size_t)321 * 642, 642, 128, 128, 642, 704, PsrcH, PsrcL, sSrc_, 5);
  setJob(2, keW1 + 256 * 642, (size_t)321 * 642, 642, 64, 64, 642, 704, PeaH, PeaL, sEa_, 5);
  setJob(3, keW2, (size_t)642 * 32, 32, 642, 704, 32, 32, PW2H, PW2L, sW2_, 5);
  setJob(4, knW1, (size_t)160 * 256, 256, 160, 160, 256, 256, Pn1H, Pn1L, sN1_, 5);
  setJob(5, knW2, (size_t)256 * 128, 128, 256, 256, 128, 128, Pn2H, Pn2L, sN2_, 5);
  setJob(6, fW0, 0, 256, 768, 768, 256, 256, Pf0H, Pf0L, 0, 1);
  setJob(7, fW1, 0, 256, 256, 256, 256, 256, Pf1H, Pf1L, 0, 1);
  setJob(8, fW2, 0, 256, 256, 256, 256, 256, Pf2H, Pf2L, 0, 1);
  setJob(9, gW0, 0, 256, 256, 256, 256, 256, Pg0H, Pg0L, 0, 1);
  setJob(10, gW1, 0, 256, 256, 256, 256, 256, Pg1H, Pg1L, 0, 1);
  k_prepack_all<<<dim3(1760, 11), 256, 0, stream>>>(jobs);

  k_gather<<<(N * 128 + 255) / 256, 256, 0, stream>>>(atomids, emb, feats_all, fH, N);
  hipMemsetAsync(cnt, 0, (size_t)N * sizeof(int), stream);
  k_edge_prep<<<(E + 255) / 256, 256, 0, stream>>>(coords, ei, E, d_arr, cnt);
  k_scan2<<<1, 1024, 0, stream>>>(cnt, N, cursor, degf);
  k_scatter<<<(E + 255) / 256, 256, 0, stream>>>(ei, E, d_arr, cursor, ssrc, sdst, sd);

  const int MT128 = (N + 127) / 128;
  const int MT64 = (N + 63) / 64;
  for (int k = 0; k < 5; ++k) {
    gemm_proj<<<dim3(MT128, 22), 256, 0, stream>>>(
        fH + k * 128, 768,
        PdstH + k * sDst_, PdstL + k * sDst_,
        PsrcH + k * sSrc_, PsrcL + k * sSrc_,
        keb1 + k * 642, ApU, BpU, planeN, N);
    hipMemsetAsync(msum, 0, (size_t)N * 32 * sizeof(float), stream);
    k_edge_mfma<<<(E + 63) / 64, 256, 0, stream>>>(
        ApU, BpU, planeN, ssrc, sdst, sd, E,
        PeaH + k * sEa_,
        keW1 + (size_t)k * 321 * 642 + (size_t)320 * 642,
        PW2H + k * sW2_,
        keb2 + k * 32, keng + k * 32, kenb + k * 32, msum);
    k_node_ln<<<(N + 3) / 4, 256, 0, stream>>>(
        msum, degf, feats_all, k, kn1g + k * 128, kn1b + k * 128,
        keng + k * 32, kenb + k * 32, hcatH, N);
    gemm_bf<<<dim3(MT64, 4), 256, 0, stream>>>(
        hcatH, 160, Pn1H + k * sN1_, Pn1L + k * sN1_, 160,
        knb1 + k * 256, nullptr, 0, t1H, 256, N, 256, 160, 1, 0);
    k_n2_resid<<<MT64, 256, 0, stream>>>(
        t1H, Pn2H + k * sN2_, Pn2L + k * sN2_, knb2 + k * 128,
        kn2g + k * 128, kn2b + k * 128, feats_all, fH, k, N);
  }

  gemm_bf<<<dim3(MT64, 4), 256, 0, stream>>>(
      fH, 768, Pf0H, Pf0L, 768, fb0, nullptr, 0, fAH, 256, N, 256, 768, 1, 1);
  gemm_bf<<<dim3(MT64, 4), 256, 0, stream>>>(
      fAH, 256, Pf1H, Pf1L, 256, fb1, nullptr, 0, fBH, 256, N, 256, 256, 1, 0);
  gemm_bf<<<dim3(MT64, 4), 256, 0, stream>>>(
      fBH, 256, Pf2H, Pf2L, 256, fb2, f1, 256, nullptr, 0, N, 256, 256, 1, 0);

  hipMemsetAsync(gsum, 0, 64 * 256 * sizeof(float), stream);
  hipMemsetAsync(gcnt, 0, 64 * sizeof(float), stream);
  k_pool2<<<(N + 63) / 64, 256, 0, stream>>>(f1, batch, gsum, gcnt, N);
  k_gdiv<<<64, 256, 0, stream>>>(gsum, gcnt, gH);
  gemm_bf<<<dim3(1, 4), 256, 0, stream>>>(
      gH, 256, Pg0H, Pg0L, 256, gb0, nullptr, 0, g1H, 256, 64, 256, 256, 1, 0);
  gemm_bf<<<dim3(1, 4), 256, 0, stream>>>(
      g1H, 256, Pg1H, Pg1L, 256, gb1, g2, 256, nullptr, 0, 64, 256, 256, 1, 0);
  k_gout<<<1, 64, 0, stream>>>(g2, gW2, gb2, (float*)d_out);
}

// Round 11
// 1784.329 us; speedup vs baseline: 1.0587x; 1.0198x over previous
//
#include <hip/hip_runtime.h>
#include <cstdint>
#include <cstddef>

// DeltaNetMolecular R11: edge kernel = R9 exact (lb(256,3) depth-2 pipeline,
// measured best 201us). msum zeroing folded into k_node_ln (-4 memset
// dispatches). k_pool2 at 16 nodes/block (was grid-starved at 157 blocks).

#define DEV __device__ __forceinline__

typedef __attribute__((ext_vector_type(8))) short bf16x8;
typedef __attribute__((ext_vector_type(4))) float f32x4;

DEV float siluf(float x) { return x / (1.f + __expf(-x)); }

DEV unsigned short f2bf(float f) {
  unsigned u = __float_as_uint(f);
  unsigned r = u + 0x7FFFu + ((u >> 16) & 1u);
  return (unsigned short)(r >> 16);
}
DEV float bf2f(unsigned short h) { return __uint_as_float(((unsigned)h) << 16); }

DEV f32x4 mfma16(bf16x8 a, bf16x8 b, f32x4 c) {
  return __builtin_amdgcn_mfma_f32_16x16x32_bf16(a, b, c, 0, 0, 0);
}

DEV void unpack8(bf16x8 v, float* o) {
#pragma unroll
  for (int j = 0; j < 8; ++j) o[j] = bf2f((unsigned short)v[j]);
}

// ------------------------------------------------- gather emb (+bf16 copy)
__global__ __launch_bounds__(256) void k_gather(const int* __restrict__ atomids,
                                                const float* __restrict__ emb,
                                                float* __restrict__ feats_all,
                                                unsigned short* __restrict__ fH, int N) {
  int idx = blockIdx.x * 256 + threadIdx.x;
  if (idx >= N * 128) return;
  int i = idx >> 7, j = idx & 127;
  float v = emb[atomids[i] * 128 + j];
  size_t o = (size_t)i * 768 + j;
  feats_all[o] = v;
  fH[o] = f2bf(v);
}

// --------------------------------------------------- edge dist + dst histogram
__global__ __launch_bounds__(256) void k_edge_prep(const float* __restrict__ coords,
                                                   const int* __restrict__ ei, int E,
                                                   float* __restrict__ d_arr,
                                                   int* __restrict__ cnt) {
  int e = blockIdx.x * 256 + threadIdx.x;
  if (e >= E) return;
  int s = ei[e], t = ei[E + e];
  float dx = coords[3 * s + 0] - coords[3 * t + 0];
  float dy = coords[3 * s + 1] - coords[3 * t + 1];
  float dz = coords[3 * s + 2] - coords[3 * t + 2];
  d_arr[e] = dx * dx + dy * dy + dz * dz;
  atomicAdd(&cnt[t], 1);
}

// -------------------- single-block scan, shuffle-based (2 barriers total)
__global__ __launch_bounds__(1024) void k_scan2(const int* __restrict__ cnt, int N,
                                                int* __restrict__ cursor,
                                                float* __restrict__ degf) {
  __shared__ int wsum[16];
  int tid = threadIdx.x;
  int chunk = (N + 1023) >> 10;
  int lo = tid * chunk, hi = min(N, lo + chunk);
  int s = 0;
  for (int i = lo; i < hi; ++i) s += cnt[i];
  int lane = tid & 63, wv = tid >> 6;
  int v = s;
#pragma unroll
  for (int off = 1; off < 64; off <<= 1) {
    int u = __shfl_up(v, off, 64);
    if (lane >= off) v += u;
  }
  if (lane == 63) wsum[wv] = v;
  __syncthreads();
  if (wv == 0 && lane < 16) {
    int w = wsum[lane];
#pragma unroll
    for (int off = 1; off < 16; off <<= 1) {
      int u = __shfl_up(w, off, 16);
      if (lane >= off) w += u;
    }
    wsum[lane] = w;
  }
  __syncthreads();
  int run = (wv ? wsum[wv - 1] : 0) + v - s;  // exclusive prefix
  for (int i = lo; i < hi; ++i) {
    int c = cnt[i];
    cursor[i] = run;
    degf[i] = fmaxf((float)c, 1.f);
    run += c;
  }
}

// ------------------------------------------------------- scatter sorted edges
__global__ __launch_bounds__(256) void k_scatter(const int* __restrict__ ei, int E,
                                                 const float* __restrict__ d_arr,
                                                 int* __restrict__ cursor,
                                                 int* __restrict__ ssrc,
                                                 int* __restrict__ sdst,
                                                 float* __restrict__ sd) {
  int e = blockIdx.x * 256 + threadIdx.x;
  if (e >= E) return;
  int s = ei[e], t = ei[E + e];
  int p = atomicAdd(&cursor[t], 1);
  ssrc[p] = s;
  sdst[p] = t;
  sd[p] = d_arr[e];
}

// ------------------------------------ merged weight prepack (one launch)
struct PPJob {
  const float* W;
  unsigned short* hi;
  unsigned short* lo;
  unsigned long long wStride, oStride;
  int ldw, K, Kpad, Nc, Npad, layers;
};
struct PPJobs { PPJob j[11]; };

__global__ __launch_bounds__(256) void k_prepack_all(PPJobs jobs) {
  PPJob jb = jobs.j[blockIdx.y];
  long long per = (long long)jb.Npad * jb.Kpad;
  long long idx = (long long)blockIdx.x * 256 + threadIdx.x;
  if (idx >= per * jb.layers) return;
  int layer = (int)(idx / per);
  int r = (int)(idx - (long long)layer * per);
  const float* W = jb.W + (size_t)layer * jb.wStride;
  int n = r / jb.Kpad, k = r - n * jb.Kpad;
  float v = (n < jb.Nc && k < jb.K) ? W[(size_t)k * jb.ldw + n] : 0.f;
  unsigned short h = f2bf(v);
  jb.hi[(size_t)layer * jb.oStride + r] = h;
  jb.lo[(size_t)layer * jb.oStride + r] = f2bf(v - bf2f(h));
}

// --------- bf16 MFMA GEMM: A bf16, B hi/lo x2, M=64 per block (grid-rich)
__global__ __launch_bounds__(256) void gemm_bf(
    const unsigned short* __restrict__ AH, int lda,
    const unsigned short* __restrict__ BH, const unsigned short* __restrict__ BL, int ldb,
    const float* __restrict__ bias,
    float* __restrict__ C, int ldc,
    unsigned short* __restrict__ CH, int ldch,
    int M, int Ncols, int K, int actOut, int actA) {
  const int t = threadIdx.x;
  const int wave = t >> 6, lane = t & 63;
  const int nl = lane & 15, quad = lane >> 4;
  const int bm = blockIdx.x * 64 + wave * 16;
  const int bn = blockIdx.y * 64;
  f32x4 zero = {0.f, 0.f, 0.f, 0.f};
  f32x4 acc[4] = {zero, zero, zero, zero};
  for (int kb = 0; kb < K; kb += 32) {
    bf16x8 ah;
    int row = bm + nl;
    if (row < M) {
      ah = *(const bf16x8*)(AH + (size_t)row * lda + kb + quad * 8);
      if (actA) {
#pragma unroll
        for (int j = 0; j < 8; ++j)
          ah[j] = (short)f2bf(siluf(bf2f((unsigned short)ah[j])));
      }
    } else {
#pragma unroll
      for (int j = 0; j < 8; ++j) ah[j] = 0;
    }
#pragma unroll
    for (int tn = 0; tn < 4; ++tn) {
      size_t boff = (size_t)(bn + tn * 16 + nl) * ldb + kb + quad * 8;
      bf16x8 bh = *(const bf16x8*)(BH + boff);
      bf16x8 bl = *(const bf16x8*)(BL + boff);
      acc[tn] = mfma16(ah, bh, acc[tn]);
      acc[tn] = mfma16(ah, bl, acc[tn]);
    }
  }
#pragma unroll
  for (int tn = 0; tn < 4; ++tn) {
    int c = bn + tn * 16 + nl;
    float bv = (bias && c < Ncols) ? bias[c] : 0.f;
#pragma unroll
    for (int r = 0; r < 4; ++r) {
      int rr = bm + quad * 4 + r;
      if (rr >= M) continue;
      float v = acc[tn][r] + bv;
      if (actOut) v = siluf(v);
      if (C && c < Ncols) C[(size_t)rr * ldc + c] = v;
      if (CH && c < Ncols) CH[(size_t)rr * ldch + c] = f2bf(v);
    }
  }
}

// --------- merged A/B projection GEMM -> bf16 chunk planes (y: 0..21, R8 form)
__global__ __launch_bounds__(256) void gemm_proj(
    const unsigned short* __restrict__ AH, int lda,
    const unsigned short* __restrict__ B1H, const unsigned short* __restrict__ B1L,
    const unsigned short* __restrict__ B2H, const unsigned short* __restrict__ B2L,
    const float* __restrict__ bias1,
    unsigned short* __restrict__ C1, unsigned short* __restrict__ C2,
    int planeN, int M) {
  const int y = blockIdx.y;
  const unsigned short* BH;
  const unsigned short* BL;
  const float* bias;
  unsigned short* CP;
  int yp;
  if (y < 11) { BH = B1H; BL = B1L; bias = bias1; CP = C1; yp = y; }
  else        { BH = B2H; BL = B2L; bias = nullptr; CP = C2; yp = y - 11; }
  const int t = threadIdx.x;
  const int wave = t >> 6, lane = t & 63;
  const int nl = lane & 15, quad = lane >> 4;
  const int bm = blockIdx.x * 128 + wave * 32;
  const int bn = yp * 64;
  f32x4 zero = {0.f, 0.f, 0.f, 0.f};
  f32x4 acc[2][4] = {{zero, zero, zero, zero}, {zero, zero, zero, zero}};
  for (int kb = 0; kb < 128; kb += 32) {
    bf16x8 ah[2];
#pragma unroll
    for (int h = 0; h < 2; ++h) {
      int row = bm + h * 16 + nl;
      if (row < M)
        ah[h] = *(const bf16x8*)(AH + (size_t)row * lda + kb + quad * 8);
      else
#pragma unroll
        for (int j = 0; j < 8; ++j) ah[h][j] = 0;
    }
#pragma unroll
    for (int tn = 0; tn < 4; ++tn) {
      size_t boff = (size_t)(bn + tn * 16 + nl) * 128 + kb + quad * 8;
      bf16x8 bh = *(const bf16x8*)(BH + boff);
      bf16x8 bl = *(const bf16x8*)(BL + boff);
#pragma unroll
      for (int h = 0; h < 2; ++h) {
        acc[h][tn] = mfma16(ah[h], bh, acc[h][tn]);
        acc[h][tn] = mfma16(ah[h], bl, acc[h][tn]);
      }
    }
  }
#pragma unroll
  for (int h = 0; h < 2; ++h) {
#pragma unroll
    for (int tn = 0; tn < 4; ++tn) {
      int c = bn + tn * 16 + nl;
      float bv = (bias && c < 642) ? bias[c] : 0.f;
#pragma unroll
      for (int r = 0; r < 4; ++r) {
        int rr = bm + h * 16 + quad * 4 + r;
        if (rr >= M) continue;
        CP[(size_t)yp * planeN + (size_t)rr * 64 + tn * 16 + nl] =
            f2bf(acc[h][tn][r] + bv);
      }
    }
  }
}

// --- fused edge kernel: depth-2 gather pipeline, drain-free weight ordering
__global__ __launch_bounds__(256, 3) void k_edge_mfma(
    const unsigned short* __restrict__ Ap, const unsigned short* __restrict__ Bp,
    int planeN,
    const int* __restrict__ ssrc, const int* __restrict__ sdst,
    const float* __restrict__ sd_g, int E,
    const unsigned short* __restrict__ WeaT,  // [704][64] bf16
    const float* __restrict__ Wea64,          // [642] fp32 (d-row of W1)
    const unsigned short* __restrict__ W2T,   // [32][704] bf16
    const float* __restrict__ b2v,
    const float* __restrict__ eng, const float* __restrict__ enb,
    float* __restrict__ msum) {
  __shared__ float sAB[4][16 * 68];           // wave-owned staging (fp32)
  __shared__ unsigned short sHh[4][16 * 72];  // wave-owned h tile (bf16)
  __shared__ float sDs[64];
  __shared__ int sSrcS[64], sDstS[64];

  const int t = threadIdx.x;
  const int wave = t >> 6, lane = t & 63;
  const int nl = lane & 15, quad = lane >> 4;
  const int e0 = blockIdx.x * 64;

  if (lane < 16) {
    int el = wave * 16 + lane;
    int e = e0 + el;
    int ec = (e < E) ? e : (E - 1);
    sSrcS[el] = ssrc[ec];
    sDstS[el] = sdst[ec];
    sDs[el] = sd_g[ec];
  }
  const int r = lane >> 2, cq = lane & 3;
  const int elr = wave * 16 + r;
  const size_t aOff = (size_t)sDstS[elr] * 64 + cq * 16;
  const size_t bOff = (size_t)sSrcS[elr] * 64 + cq * 16;
  const float dR = sDs[elr];
  float* myAB = sAB[wave];
  unsigned short* myH = sHh[wave];

  bf16x8 pa0[2], pa1[2], pb0[2], pb1[2];  // depth-2 staging slots
  bf16x8 w1[4][2], w2[2][2][2];           // w2[buf][tn][ks]

  auto loadW1 = [&](int c) {
#pragma unroll
    for (int tn = 0; tn < 4; ++tn)
#pragma unroll
      for (int ks = 0; ks < 2; ++ks)
        w1[tn][ks] = *(const bf16x8*)(WeaT + (size_t)(c * 64 + tn * 16 + nl) * 64 +
                                      ks * 32 + quad * 8);
  };
  auto loadW2 = [&](int c, int buf) {
#pragma unroll
    for (int tn = 0; tn < 2; ++tn)
#pragma unroll
      for (int ks = 0; ks < 2; ++ks)
        w2[buf][tn][ks] = *(const bf16x8*)(W2T + (size_t)(tn * 16 + nl) * 704 +
                                           c * 64 + ks * 32 + quad * 8);
  };
  auto issue = [&](int c, int s) {
    const unsigned short* a = Ap + (size_t)c * planeN + aOff;
    const unsigned short* b = Bp + (size_t)c * planeN + bOff;
    pa0[s] = *(const bf16x8*)a;
    pa1[s] = *(const bf16x8*)(a + 8);
    pb0[s] = *(const bf16x8*)b;
    pb1[s] = *(const bf16x8*)(b + 8);
  };
  auto commit = [&](int c, int s) {
    float za[16], zb[16], w[16];
    unpack8(pa0[s], za); unpack8(pa1[s], za + 8);
    unpack8(pb0[s], zb); unpack8(pb1[s], zb + 8);
    const int cb = c * 64 + cq * 16;
    if (cb + 15 < 642) {
#pragma unroll
      for (int j = 0; j < 4; ++j) {
        f32x4 wv = *(const f32x4*)(Wea64 + cb + 4 * j);
        w[4 * j] = wv.x; w[4 * j + 1] = wv.y; w[4 * j + 2] = wv.z; w[4 * j + 3] = wv.w;
      }
    } else {
#pragma unroll
      for (int u = 0; u < 16; ++u) w[u] = (cb + u < 642) ? Wea64[cb + u] : 0.f;
    }
#pragma unroll
    for (int j = 0; j < 4; ++j) {
      f32x4 o;
#pragma unroll
      for (int u = 0; u < 4; ++u) o[u] = za[4 * j + u] + zb[4 * j + u] + dR * w[4 * j + u];
      *(f32x4*)(myAB + r * 68 + cq * 16 + 4 * j) = o;
    }
  };

  issue(0, 0);  // oldest in flight
  bf16x8 eaHi[2];
  {
    float d = sDs[wave * 16 + nl];
#pragma unroll
    for (int ks = 0; ks < 2; ++ks)
#pragma unroll
      for (int j = 0; j < 8; ++j) {
        int k = ks * 32 + quad * 8 + j;
        float arg = d * exp2f(-(float)(k & 31));
        float v = (k < 32) ? __sinf(arg) : __cosf(arg);
        eaHi[ks][j] = (short)f2bf(v);
      }
  }
  loadW1(0);
  loadW2(0, 0);
  loadW2(1, 1);
  issue(1, 1);  // depth-2: second chunk in flight

  f32x4 zero = {0.f, 0.f, 0.f, 0.f};
  f32x4 macc[2] = {zero, zero};

#pragma unroll
  for (int c = 0; c < 11; ++c) {
    commit(c, c & 1);  // ONLY gather wait; 2 chunks of cover
    // GEMM1 (zero-seeded; staged add after, overlapping MFMA latency)
    f32x4 acc1[4] = {zero, zero, zero, zero};
#pragma unroll
    for (int tn = 0; tn < 4; ++tn)
#pragma unroll
      for (int ks = 0; ks < 2; ++ks) acc1[tn] = mfma16(eaHi[ks], w1[tn][ks], acc1[tn]);
#pragma unroll
    for (int tn = 0; tn < 4; ++tn)
#pragma unroll
      for (int rr = 0; rr < 4; ++rr) {
        int lrow = quad * 4 + rr;
        float z = acc1[tn][rr] + myAB[lrow * 68 + tn * 16 + nl];
        myH[lrow * 72 + tn * 16 + nl] = f2bf(siluf(z));
      }
    if (c < 10) loadW1(c + 1);  // w1 free after gemm1
    // GEMM2: h (bf16, wave-owned rows) @ W2 chunk — w2(c) drained at commit
#pragma unroll
    for (int ks = 0; ks < 2; ++ks) {
      bf16x8 ah = *(const bf16x8*)(myH + nl * 72 + ks * 32 + quad * 8);
#pragma unroll
      for (int tn = 0; tn < 2; ++tn) macc[tn] = mfma16(ah, w2[c & 1][tn][ks], macc[tn]);
    }
    if (c < 9) {
      loadW2(c + 2, c & 1);  // buf freed by gemm2 above
      issue(c + 2, c & 1);   // slot freed by commit above
    }
  }

  // epilogue: bias+silu+LN(32) via width-16 shuffles -> sM (fp32, in sAB)
  float g0 = eng[nl], g1v = eng[16 + nl], bb0 = enb[nl], bb1 = enb[16 + nl];
  float bi0 = b2v[nl], bi1 = b2v[16 + nl];
  float* sMw = myAB;  // rows 0..15 stride 33
#pragma unroll
  for (int rr = 0; rr < 4; ++rr) {
    float v0 = siluf(macc[0][rr] + bi0);
    float v1 = siluf(macc[1][rr] + bi1);
    float s = v0 + v1;
    float ss = v0 * v0 + v1 * v1;
#pragma unroll
    for (int m = 1; m < 16; m <<= 1) {
      s += __shfl_xor(s, m, 16);
      ss += __shfl_xor(ss, m, 16);
    }
    float mu = s * (1.f / 32.f);
    float var = ss * (1.f / 32.f) - mu * mu;
    float rs = rsqrtf(var + 1e-5f);
    int lr = quad * 4 + rr;
    sMw[lr * 33 + nl] = (v0 - mu) * rs * g0 + bb0;
    sMw[lr * 33 + 16 + nl] = (v1 - mu) * rs * g1v + bb1;
  }
  __syncthreads();  // only barrier: cross-wave sM/sDstS visibility
  {
    int col = t & 31, seg = t >> 5;
    float acc = 0.f;
    int cur = -1;
#pragma unroll
    for (int i = 0; i < 8; ++i) {
      int e = seg * 8 + i;
      int dn = (e0 + e < E) ? sDstS[e] : -1;
      if (dn != cur) {
        if (cur >= 0) atomicAdd(&msum[(size_t)cur * 32 + col], acc);
        acc = 0.f;
        cur = dn;
      }
      if (dn >= 0) acc += sAB[e >> 4][(e & 15) * 33 + col];
    }
    if (cur >= 0) atomicAdd(&msum[(size_t)cur * 32 + col], acc);
  }
}

// ---------- node-side LN + concat builder (bf16 out); zeroes msum after read
__global__ __launch_bounds__(256) void k_node_ln(
    float* __restrict__ msum, const float* __restrict__ deg,
    const float* __restrict__ featsAll, int k,
    const float* __restrict__ n1g, const float* __restrict__ n1b,
    const float* __restrict__ eng, const float* __restrict__ enb,
    unsigned short* __restrict__ hcatH, int N) {
  int node = blockIdx.x * 4 + (threadIdx.x >> 6);
  int lane = threadIdx.x & 63;
  if (node >= N) return;
  const float* fr = featsAll + (size_t)node * 768 + k * 128;
  float x0 = fr[lane], x1 = fr[64 + lane];
  float s = x0 + x1;
#pragma unroll
  for (int m = 1; m < 64; m <<= 1) s += __shfl_xor(s, m, 64);
  float mu = s * (1.f / 128.f);
  float d0 = x0 - mu, d1 = x1 - mu;
  float v = d0 * d0 + d1 * d1;
#pragma unroll
  for (int m = 1; m < 64; m <<= 1) v += __shfl_xor(v, m, 64);
  float rstd = rsqrtf(v * (1.f / 128.f) + 1e-5f);
  size_t hb = (size_t)node * 160;
  hcatH[hb + lane] = f2bf(d0 * rstd * n1g[lane] + n1b[lane]);
  hcatH[hb + 64 + lane] = f2bf(d1 * rstd * n1g[64 + lane] + n1b[64 + lane]);
  float dg = deg[node];
  int col = lane & 31;
  float y = msum[(size_t)node * 32 + col] / dg;
  // zero msum for the NEXT layer's edge kernel (replaces a memset dispatch)
  if (lane < 32) msum[(size_t)node * 32 + col] = 0.f;
  float sy = y;
#pragma unroll
  for (int m = 1; m < 32; m <<= 1) sy += __shfl_xor(sy, m, 32);
  float mu2 = sy * (1.f / 32.f);
  float dy = y - mu2;
  float vy = dy * dy;
#pragma unroll
  for (int m = 1; m < 32; m <<= 1) vy += __shfl_xor(vy, m, 32);
  float rstd2 = rsqrtf(vy * (1.f / 32.f) + 1e-5f);
  if (lane < 32) hcatH[hb + 128 + col] = f2bf(dy * rstd2 * eng[col] + enb[col]);
}

// ------------- fused n2 GEMM + LayerNorm + residual (block = 64 rows x 128)
__global__ __launch_bounds__(256) void k_n2_resid(
    const unsigned short* __restrict__ t1H,
    const unsigned short* __restrict__ BH, const unsigned short* __restrict__ BL,
    const float* __restrict__ b2,
    const float* __restrict__ n2g, const float* __restrict__ n2b,
    float* __restrict__ featsAll, unsigned short* __restrict__ fH, int k, int N) {
  const int t = threadIdx.x;
  const int wave = t >> 6, lane = t & 63;
  const int nl = lane & 15, quad = lane >> 4;
  const int bm = blockIdx.x * 64 + wave * 16;
  f32x4 zero = {0.f, 0.f, 0.f, 0.f};
  f32x4 acc[8] = {zero, zero, zero, zero, zero, zero, zero, zero};
  for (int kb = 0; kb < 256; kb += 32) {
    bf16x8 ah;
    int row = bm + nl;
    if (row < N)
      ah = *(const bf16x8*)(t1H + (size_t)row * 256 + kb + quad * 8);
    else
#pragma unroll
      for (int j = 0; j < 8; ++j) ah[j] = 0;
#pragma unroll
    for (int tn = 0; tn < 8; ++tn) {
      size_t boff = (size_t)(tn * 16 + nl) * 256 + kb + quad * 8;
      bf16x8 bh = *(const bf16x8*)(BH + boff);
      bf16x8 bl = *(const bf16x8*)(BL + boff);
      acc[tn] = mfma16(ah, bh, acc[tn]);
      acc[tn] = mfma16(ah, bl, acc[tn]);
    }
  }
  float bv[8], gv[8], bb[8];
#pragma unroll
  for (int tn = 0; tn < 8; ++tn) {
    int col = tn * 16 + nl;
    bv[tn] = b2[col];
    gv[tn] = n2g[col];
    bb[tn] = n2b[col];
  }
#pragma unroll
  for (int r = 0; r < 4; ++r) {
    int row = bm + quad * 4 + r;
    float v[8];
    float s = 0.f, ss = 0.f;
#pragma unroll
    for (int tn = 0; tn < 8; ++tn) {
      v[tn] = acc[tn][r] + bv[tn];
      s += v[tn];
      ss += v[tn] * v[tn];
    }
#pragma unroll
    for (int m = 1; m < 16; m <<= 1) {
      s += __shfl_xor(s, m, 16);
      ss += __shfl_xor(ss, m, 16);
    }
    float mu = s * (1.f / 128.f);
    float var = ss * (1.f / 128.f) - mu * mu;
    float rs = rsqrtf(var + 1e-5f);
    if (row < N) {
      const float* fk = featsAll + (size_t)row * 768 + k * 128;
      size_t ob = (size_t)row * 768 + (k + 1) * 128;
#pragma unroll
      for (int tn = 0; tn < 8; ++tn) {
        int col = tn * 16 + nl;
        float o = fk[col] + (v[tn] - mu) * rs * gv[tn] + bb[tn];
        featsAll[ob + col] = o;
        fH[ob + col] = f2bf(o);
      }
    }
  }
}

// ------------- graph pooling (batch sorted -> runs), 16 nodes/block
__global__ __launch_bounds__(256) void k_pool2(const float* __restrict__ f,
                                               const int* __restrict__ batch,
                                               float* __restrict__ gsum,
                                               float* __restrict__ gcnt, int N) {
  int n0 = blockIdx.x * 16;
  int col = threadIdx.x;
  float acc = 0.f;
  int cur = -1;
  for (int i = 0; i < 16; ++i) {
    int n = n0 + i;
    if (n >= N) break;
    int b = batch[n];
    if (b != cur) {
      if (cur >= 0) atomicAdd(&gsum[cur * 256 + col], acc);
      acc = 0.f;
      cur = b;
    }
    acc += f[(size_t)n * 256 + col];
  }
  if (cur >= 0) atomicAdd(&gsum[cur * 256 + col], acc);
  if (threadIdx.x == 0) {
    int cnt = 0;
    cur = -1;
    for (int i = 0; i < 16; ++i) {
      int n = n0 + i;
      if (n >= N) break;
      int b = batch[n];
      if (b != cur) {
        if (cur >= 0) atomicAdd(&gcnt[cur], (float)cnt);
        cnt = 0;
        cur = b;
      }
      cnt++;
    }
    if (cur >= 0) atomicAdd(&gcnt[cur], (float)cnt);
  }
}

__global__ void k_gdiv(float* gsum, const float* gcnt, unsigned short* gH) {
  int b = blockIdx.x, j = threadIdx.x;
  float v = gsum[b * 256 + j] / fmaxf(gcnt[b], 1.f);
  gH[b * 256 + j] = f2bf(v);
}

__global__ void k_gout(const float* __restrict__ g2, const float* __restrict__ gW2,
                       const float* __restrict__ gb2, float* __restrict__ out) {
  int b = threadIdx.x;
  if (b >= 64) return;
  float s = gb2[0];
  for (int j = 0; j < 256; ++j) s += g2[b * 256 + j] * gW2[j];
  out[b] = s;
}

// ------------------------------------------------------------------- launch
extern "C" void kernel_launch(void* const* d_in, const int* in_sizes, int n_in,
                              void* d_out, int out_size, void* d_ws, size_t ws_size,
                              hipStream_t stream) {
  const float* coords = (const float*)d_in[0];
  const int* atomids = (const int*)d_in[1];
  const int* ei = (const int*)d_in[2];
  const int* batch = (const int*)d_in[3];
  const float* emb = (const float*)d_in[5];
  const float* keW1 = (const float*)d_in[6];
  const float* keb1 = (const float*)d_in[7];
  const float* keW2 = (const float*)d_in[8];
  const float* keb2 = (const float*)d_in[9];
  const float* keng = (const float*)d_in[10];
  const float* kenb = (const float*)d_in[11];
  const float* kn1g = (const float*)d_in[12];
  const float* kn1b = (const float*)d_in[13];
  const float* knW1 = (const float*)d_in[14];
  const float* knb1 = (const float*)d_in[15];
  const float* knW2 = (const float*)d_in[16];
  const float* knb2 = (const float*)d_in[17];
  const float* kn2g = (const float*)d_in[18];
  const float* kn2b = (const float*)d_in[19];
  const float* fW0 = (const float*)d_in[20];
  const float* fb0 = (const float*)d_in[21];
  const float* fW1 = (const float*)d_in[22];
  const float* fb1 = (const float*)d_in[23];
  const float* fW2 = (const float*)d_in[24];
  const float* fb2 = (const float*)d_in[25];
  const float* gW0 = (const float*)d_in[26];
  const float* gb0 = (const float*)d_in[27];
  const float* gW1 = (const float*)d_in[28];
  const float* gb1 = (const float*)d_in[29];
  const float* gW2 = (const float*)d_in[30];
  const float* gb2 = (const float*)d_in[31];

  const int N = in_sizes[0] / 3;
  const int E = in_sizes[2] / 2;
  const int planeN = N * 64;

  size_t off = 0;
  auto alloc = [&](size_t n) {
    float* p = (float*)d_ws + off;
    off += (n + 63) & ~(size_t)63;
    return p;
  };
  float* feats_all = alloc((size_t)N * 768);
  float* d_arr = alloc(E);
  float* degf = alloc(N);
  float* msum = alloc((size_t)N * 32);
  float* f1 = alloc((size_t)N * 256);
  float* gsum = alloc(64 * 256);
  float* gcnt = alloc(64);
  float* g2 = alloc(64 * 256);
  int* cnt = (int*)alloc(N);
  int* cursor = (int*)alloc(N);
  int* ssrc = (int*)alloc(E);
  int* sdst = (int*)alloc(E);
  float* sd = alloc(E);

  unsigned short* ubase = (unsigned short*)(alloc(0));
  size_t uoff = 0;
  auto ualloc = [&](size_t n) {
    unsigned short* p = ubase + uoff;
    uoff += (n + 63) & ~(size_t)63;
    return p;
  };
  unsigned short* fH = ualloc((size_t)N * 768);
  unsigned short* ApU = ualloc((size_t)11 * planeN);
  unsigned short* BpU = ualloc((size_t)11 * planeN);
  unsigned short* hcatH = ualloc((size_t)N * 160);
  unsigned short* t1H = ualloc((size_t)N * 256);
  unsigned short* fAH = ualloc((size_t)N * 256);
  unsigned short* fBH = ualloc((size_t)N * 256);
  unsigned short* gH = ualloc(64 * 256);
  unsigned short* g1H = ualloc(64 * 256);
  const size_t sDst_ = 704 * 128, sSrc_ = 704 * 128, sEa_ = 704 * 64;
  const size_t sW2_ = 32 * 704, sN1_ = 256 * 160, sN2_ = 128 * 256;
  unsigned short* PdstH = ualloc(5 * sDst_); unsigned short* PdstL = ualloc(5 * sDst_);
  unsigned short* PsrcH = ualloc(5 * sSrc_); unsigned short* PsrcL = ualloc(5 * sSrc_);
  unsigned short* PeaH = ualloc(5 * sEa_);   unsigned short* PeaL = ualloc(5 * sEa_);
  unsigned short* PW2H = ualloc(5 * sW2_);   unsigned short* PW2L = ualloc(5 * sW2_);
  unsigned short* Pn1H = ualloc(5 * sN1_);   unsigned short* Pn1L = ualloc(5 * sN1_);
  unsigned short* Pn2H = ualloc(5 * sN2_);   unsigned short* Pn2L = ualloc(5 * sN2_);
  unsigned short* Pf0H = ualloc(256 * 768);  unsigned short* Pf0L = ualloc(256 * 768);
  unsigned short* Pf1H = ualloc(256 * 256);  unsigned short* Pf1L = ualloc(256 * 256);
  unsigned short* Pf2H = ualloc(256 * 256);  unsigned short* Pf2L = ualloc(256 * 256);
  unsigned short* Pg0H = ualloc(256 * 256);  unsigned short* Pg0L = ualloc(256 * 256);
  unsigned short* Pg1H = ualloc(256 * 256);  unsigned short* Pg1L = ualloc(256 * 256);

  PPJobs jobs;
  auto setJob = [&](int i, const float* W, size_t wStr, int ldw, int K, int Kpad,
                    int Nc, int Npad, unsigned short* hi, unsigned short* lo,
                    size_t oStr, int layers) {
    jobs.j[i] = PPJob{W, hi, lo, (unsigned long long)wStr, (unsigned long long)oStr,
                      ldw, K, Kpad, Nc, Npad, layers};
  };
  setJob(0, keW1, (size_t)321 * 642, 642, 128, 128, 642, 704, PdstH, PdstL, sDst_, 5);
  setJob(1, keW1 + 128 * 642, (size_t)321 * 642, 642, 128, 128, 642, 704, PsrcH, PsrcL, sSrc_, 5);
  setJob(2, keW1 + 256 * 642, (size_t)321 * 642, 642, 64, 64, 642, 704, PeaH, PeaL, sEa_, 5);
  setJob(3, keW2, (size_t)642 * 32, 32, 642, 704, 32, 32, PW2H, PW2L, sW2_, 5);
  setJob(4, knW1, (size_t)160 * 256, 256, 160, 160, 256, 256, Pn1H, Pn1L, sN1_, 5);
  setJob(5, knW2, (size_t)256 * 128, 128, 256, 256, 128, 128, Pn2H, Pn2L, sN2_, 5);
  setJob(6, fW0, 0, 256, 768, 768, 256, 256, Pf0H, Pf0L, 0, 1);
  setJob(7, fW1, 0, 256, 256, 256, 256, 256, Pf1H, Pf1L, 0, 1);
  setJob(8, fW2, 0, 256, 256, 256, 256, 256, Pf2H, Pf2L, 0, 1);
  setJob(9, gW0, 0, 256, 256, 256, 256, 256, Pg0H, Pg0L, 0, 1);
  setJob(10, gW1, 0, 256, 256, 256, 256, 256, Pg1H, Pg1L, 0, 1);
  k_prepack_all<<<dim3(1760, 11), 256, 0, stream>>>(jobs);

  k_gather<<<(N * 128 + 255) / 256, 256, 0, stream>>>(atomids, emb, feats_all, fH, N);
  hipMemsetAsync(cnt, 0, (size_t)N * sizeof(int), stream);
  hipMemsetAsync(msum, 0, (size_t)N * 32 * sizeof(float), stream);
  k_edge_prep<<<(E + 255) / 256, 256, 0, stream>>>(coords, ei, E, d_arr, cnt);
  k_scan2<<<1, 1024, 0, stream>>>(cnt, N, cursor, degf);
  k_scatter<<<(E + 255) / 256, 256, 0, stream>>>(ei, E, d_arr, cursor, ssrc, sdst, sd);

  const int MT128 = (N + 127) / 128;
  const int MT64 = (N + 63) / 64;
  for (int k = 0; k < 5; ++k) {
    gemm_proj<<<dim3(MT128, 22), 256, 0, stream>>>(
        fH + k * 128, 768,
        PdstH + k * sDst_, PdstL + k * sDst_,
        PsrcH + k * sSrc_, PsrcL + k * sSrc_,
        keb1 + k * 642, ApU, BpU, planeN, N);
    k_edge_mfma<<<(E + 63) / 64, 256, 0, stream>>>(
        ApU, BpU, planeN, ssrc, sdst, sd, E,
        PeaH + k * sEa_,
        keW1 + (size_t)k * 321 * 642 + (size_t)320 * 642,
        PW2H + k * sW2_,
        keb2 + k * 32, keng + k * 32, kenb + k * 32, msum);
    k_node_ln<<<(N + 3) / 4, 256, 0, stream>>>(
        msum, degf, feats_all, k, kn1g + k * 128, kn1b + k * 128,
        keng + k * 32, kenb + k * 32, hcatH, N);
    gemm_bf<<<dim3(MT64, 4), 256, 0, stream>>>(
        hcatH, 160, Pn1H + k * sN1_, Pn1L + k * sN1_, 160,
        knb1 + k * 256, nullptr, 0, t1H, 256, N, 256, 160, 1, 0);
    k_n2_resid<<<MT64, 256, 0, stream>>>(
        t1H, Pn2H + k * sN2_, Pn2L + k * sN2_, knb2 + k * 128,
        kn2g + k * 128, kn2b + k * 128, feats_all, fH, k, N);
  }

  gemm_bf<<<dim3(MT64, 4), 256, 0, stream>>>(
      fH, 768, Pf0H, Pf0L, 768, fb0, nullptr, 0, fAH, 256, N, 256, 768, 1, 1);
  gemm_bf<<<dim3(MT64, 4), 256, 0, stream>>>(
      fAH, 256, Pf1H, Pf1L, 256, fb1, nullptr, 0, fBH, 256, N, 256, 256, 1, 0);
  gemm_bf<<<dim3(MT64, 4), 256, 0, stream>>>(
      fBH, 256, Pf2H, Pf2L, 256, fb2, f1, 256, nullptr, 0, N, 256, 256, 1, 0);

  hipMemsetAsync(gsum, 0, 64 * 256 * sizeof(float), stream);
  hipMemsetAsync(gcnt, 0, 64 * sizeof(float), stream);
  k_pool2<<<(N + 15) / 16, 256, 0, stream>>>(f1, batch, gsum, gcnt, N);
  k_gdiv<<<64, 256, 0, stream>>>(gsum, gcnt, gH);
  gemm_bf<<<dim3(1, 4), 256, 0, stream>>>(
      gH, 256, Pg0H, Pg0L, 256, gb0, nullptr, 0, g1H, 256, 64, 256, 256, 1, 0);
  gemm_bf<<<dim3(1, 4), 256, 0, stream>>>(
      g1H, 256, Pg1H, Pg1L, 256, gb1, g2, 256, nullptr, 0, 64, 256, 256, 1, 0);
  k_gout<<<1, 64, 0, stream>>>(g2, gW2, gb2, (float*)d_out);
}